// Round 1
// baseline (293.499 us; speedup 1.0000x reference)
//
#include <hip/hip_runtime.h>
#include <hip/hip_bf16.h>

// Flash-attention formulation of memory_fuse:
//   B=16, C=256, N=T*H*W=4608 (kv tokens), M=H*W=576 (q tokens)
//   S[n,m] = sum_c fm[c,n]*fq[c,m]/16 ; attn = softmax_n(S) ; y[m,c] = sum_n fm[c,n]*attn[n,m]
// bf16 MFMA 32x32x16, f32 accum, online softmax with defer-max (THR=8),
// 4-way N-split across blocks + f32 partial merge kernel (ws fallback to 1-split).

#define Bc 16
#define Cc 256
#define Nc 4608
#define Mc 576

typedef short bf16x8 __attribute__((ext_vector_type(8)));   // 8 bf16 (guide-verified operand type)
typedef short bf16x4 __attribute__((ext_vector_type(4)));
typedef float f32x16 __attribute__((ext_vector_type(16)));

static __device__ __forceinline__ short f2bf(float f) {
  return __builtin_bit_cast(short, __float2bfloat16(f));    // RNE f32->bf16
}

// LDS layout (bytes):
//   kT  [64][256] bf16  @ 0      : fm tile, [n][c], 16B-block xor-swizzled by (n&7)  (QK^T A-frags)
//   kN  [256][64] bf16  @ 32768  : fm tile, [c][n], 16B-block xor-swizzled by (c&7)  (PV B-frags)
//   pB  [4][32][40] bf16 @ 65536 : per-wave P tile [m][n], rows padded to 80B
//   stm/stl/stsc/stLg [4][32] f32 @ 75776.. : softmax stats broadcast buffers
//   xch (reuses kT+kN after main loop): [2][32][256] f32 ni-merge exchange
__global__ __launch_bounds__(256, 2)
void attn_main(const float* __restrict__ fm, const float* __restrict__ fq,
               float* __restrict__ outp, float* __restrict__ mstat,
               float* __restrict__ lstat, const int nsplit, const int nsuper)
{
  __shared__ __align__(16) char smem[77824];
  short* kT  = (short*)smem;
  short* kN  = (short*)(smem + 32768);
  short* pB  = (short*)(smem + 65536);
  float* stm = (float*)(smem + 75776);
  float* stl = (float*)(smem + 76288);
  float* stsc= (float*)(smem + 76800);
  float* stLg= (float*)(smem + 77312);
  float* xch = (float*)smem;

  const int tid  = threadIdx.x;
  const int lane = tid & 63;
  const int l31  = lane & 31;
  const int g    = lane >> 5;
  const int wv   = tid >> 6;
  const int mi   = wv & 1;
  const int ni   = wv >> 1;

  // XCD-clustered block-id remap: the 9 q-blocks sharing one (b,split) fm slice
  // become consecutive logical ids on one XCD (grid divisible by 8).
  const int nblk = gridDim.x;
  const int cpx  = nblk >> 3;
  const int bid  = blockIdx.x;
  const int lid  = (bid & 7) * cpx + (bid >> 3);
  const int qt = lid % 9;
  const int bs = lid / 9;
  const int b  = bs & 15;
  const int s  = bs >> 4;

  const int m0 = qt * 64 + mi * 32;
  const int n0 = s * (Nc / nsplit);

  // Hoisted Q fragments (QK^T B-operand: B[k=c][m], lane holds k=kt*16+g*8+j, m=m0+l31).
  // Fold the 1/sqrt(C)=1/16 scale into Q before bf16 conversion.
  bf16x8 qf[16];
  {
    const float* fqb = fq + (size_t)b * Cc * Mc + m0 + l31;
    #pragma unroll
    for (int kt = 0; kt < 16; ++kt) {
      bf16x8 q;
      #pragma unroll
      for (int j = 0; j < 8; ++j) {
        const int c = kt * 16 + g * 8 + j;
        q[j] = f2bf(fqb[c * Mc] * 0.0625f);
      }
      qf[kt] = q;
    }
  }

  f32x16 acc[8];                      // PV accum D[m][c]: 8 c-tiles of 32
  #pragma unroll
  for (int i = 0; i < 8; ++i)
    #pragma unroll
    for (int e = 0; e < 16; ++e) acc[i][e] = 0.f;
  float mr = -1e30f, lr = 0.f;        // online-softmax state for column m=m0+l31

  const float* fmb = fm + (size_t)b * Cc * Nc;
  const int tb = ni * 32;             // this wave's n-parity tile base within the 64-n super-tile

  for (int it = 0; it < nsuper; ++it) {
    const int nb = n0 + it * 64;
    __syncthreads();                  // prev compute done; LDS reusable
    // ---- stage 64n x 256c fp32->bf16 into both layouts (16 float4 per thread)
    #pragma unroll 2
    for (int i = 0; i < 8; ++i) {
      const int idx = i * 256 + tid;        // [0,2048)
      const int c   = (idx >> 4) * 2;       // even c; handles rows c and c+1
      const int n4  = idx & 15;             // n = 4*n4..4*n4+3
      const float* src = fmb + (size_t)c * Nc + nb + n4 * 4;
      const float4 va = *(const float4*)src;
      const float4 vb = *(const float4*)(src + Nc);
      bf16x4 sa, sb;
      sa[0]=f2bf(va.x); sa[1]=f2bf(va.y); sa[2]=f2bf(va.z); sa[3]=f2bf(va.w);
      sb[0]=f2bf(vb.x); sb[1]=f2bf(vb.y); sb[2]=f2bf(vb.z); sb[3]=f2bf(vb.w);
      const int bn = n4 >> 1, off = (n4 & 1) * 4;
      *(bf16x4*)&kN[c * 64       + ((bn ^ (c & 7))       << 3) + off] = sa;
      *(bf16x4*)&kN[(c + 1) * 64 + ((bn ^ ((c + 1) & 7)) << 3) + off] = sb;
      const int cb = c >> 3;
      #pragma unroll
      for (int k = 0; k < 4; ++k) {
        const int row = n4 * 4 + k;
        const unsigned pk = (unsigned short)sa[k] | ((unsigned)(unsigned short)sb[k] << 16);
        *(unsigned*)&kT[row * 256 + ((cb ^ (row & 7)) << 3) + (c & 7)] = pk;
      }
    }
    __syncthreads();

    // ---- QK^T: S[n(32) x m(32)] ; A = K-tile (A[n][c]), B = hoisted Q
    f32x16 sacc;
    #pragma unroll
    for (int e = 0; e < 16; ++e) sacc[e] = 0.f;
    const int nrow = tb + l31;
    const short* kTr = &kT[nrow * 256];
    const int sw = nrow & 7;
    #pragma unroll
    for (int kt = 0; kt < 16; ++kt) {
      const bf16x8 a = *(const bf16x8*)&kTr[((2 * kt + g) ^ sw) << 3];
      sacc = __builtin_amdgcn_mfma_f32_32x32x16_bf16(a, qf[kt], sacc, 0, 0, 0);
    }

    // ---- online softmax over n (rows). Lane owns column m = m0+l31.
    float pmax = sacc[0];
    #pragma unroll
    for (int r = 1; r < 16; ++r) pmax = fmaxf(pmax, sacc[r]);
    pmax = fmaxf(pmax, __shfl_xor(pmax, 32));

    if (!__all(pmax <= mr + 8.f)) {   // defer-max: rescale is rare
      const float mn = fmaxf(mr, pmax);
      const float sc = __expf(mr - mn);
      lr *= sc;
      mr = mn;
      if (g == 0) stsc[wv * 32 + l31] = sc;   // per-column scale -> broadcast by row
      #pragma unroll
      for (int r = 0; r < 16; ++r) {
        const int rowm = (r & 3) + 8 * (r >> 2) + 4 * g;
        const float sr = stsc[wv * 32 + rowm];
        #pragma unroll
        for (int ct = 0; ct < 8; ++ct) acc[ct][r] *= sr;
      }
    }

    // P = exp(S - mr) -> bf16 into pB[m][n]; col-sum into lr
    float csum = 0.f;
    short* pw_ = &pB[(wv * 32 + l31) * 40];
    #pragma unroll
    for (int q4 = 0; q4 < 4; ++q4) {          // reg quad q4 holds rows n = 8*q4 + 4*g + 0..3
      const float e0 = __expf(sacc[q4*4+0] - mr);
      const float e1 = __expf(sacc[q4*4+1] - mr);
      const float e2 = __expf(sacc[q4*4+2] - mr);
      const float e3 = __expf(sacc[q4*4+3] - mr);
      csum += (e0 + e1) + (e2 + e3);
      bf16x4 pk;
      pk[0]=f2bf(e0); pk[1]=f2bf(e1); pk[2]=f2bf(e2); pk[3]=f2bf(e3);
      *(bf16x4*)&pw_[q4 * 8 + g * 4] = pk;
    }
    csum += __shfl_xor(csum, 32);
    lr += csum;

    // ---- PV: acc[m][c] += P(A[m][n]) * fm(B[n][c], natural layout kN)
    const short* pr_ = &pB[(wv * 32 + l31) * 40];
    const bf16x8 pf0 = *(const bf16x8*)&pr_[g * 8];        // k = 0..15 slice
    const bf16x8 pf1 = *(const bf16x8*)&pr_[16 + g * 8];   // k = 16..31 slice
    #pragma unroll
    for (int ct = 0; ct < 8; ++ct) {
      const int crow = ct * 32 + l31;
      const short* kNr = &kN[crow * 64];
      const int swc = crow & 7;
      const bf16x8 b0 = *(const bf16x8*)&kNr[((4 * ni + g)     ^ swc) << 3];
      const bf16x8 b1 = *(const bf16x8*)&kNr[((4 * ni + 2 + g) ^ swc) << 3];
      acc[ct] = __builtin_amdgcn_mfma_f32_32x32x16_bf16(pf0, b0, acc[ct], 0, 0, 0);
      acc[ct] = __builtin_amdgcn_mfma_f32_32x32x16_bf16(pf1, b1, acc[ct], 0, 0, 0);
    }
  }

  // ---- merge the two n-parity waves (ni=1 -> ni=0 via LDS), then write out
  __syncthreads();
  if (g == 0) { stm[wv * 32 + l31] = mr; stl[wv * 32 + l31] = lr; }
  __syncthreads();
  const int pwv = wv ^ 2;
  const float mo = stm[pwv * 32 + l31];
  const float lo = stl[pwv * 32 + l31];
  const float Mg  = fmaxf(mr, mo);
  const float wsf = __expf(mr - Mg);
  const float Lg  = wsf * lr + __expf(mo - Mg) * lo;
  if (g == 0) { stsc[wv * 32 + l31] = wsf; stLg[wv * 32 + l31] = Lg; }

  float wrow[16], Lrow[16];
  #pragma unroll
  for (int r = 0; r < 16; ++r) {
    const int rowm = (r & 3) + 8 * (r >> 2) + 4 * g;
    wrow[r] = stsc[wv * 32 + rowm];
    Lrow[r] = stLg[wv * 32 + rowm];
  }
  if (ni == 1) {
    #pragma unroll
    for (int r = 0; r < 16; ++r) {
      const int rowm = (r & 3) + 8 * (r >> 2) + 4 * g;
      float* dst = &xch[(mi * 32 + rowm) * 256 + l31];
      #pragma unroll
      for (int ct = 0; ct < 8; ++ct) dst[ct * 32] = acc[ct][r] * wrow[r];
    }
  }
  __syncthreads();
  if (ni == 0) {
    if (nsplit == 1) {
      float* ob = outp + ((size_t)b * Mc + m0) * Cc;
      #pragma unroll
      for (int r = 0; r < 16; ++r) {
        const int rowm = (r & 3) + 8 * (r >> 2) + 4 * g;
        const float* sx = &xch[(mi * 32 + rowm) * 256 + l31];
        const float rinv = 1.f / Lrow[r];
        float* orow = ob + (size_t)rowm * Cc + l31;
        #pragma unroll
        for (int ct = 0; ct < 8; ++ct)
          orow[ct * 32] = (acc[ct][r] * wrow[r] + sx[ct * 32]) * rinv;
      }
    } else {
      float* pb_ = outp + ((size_t)(s * Bc + b) * Mc + m0) * Cc;
      #pragma unroll
      for (int r = 0; r < 16; ++r) {
        const int rowm = (r & 3) + 8 * (r >> 2) + 4 * g;
        const float* sx = &xch[(mi * 32 + rowm) * 256 + l31];
        float* orow = pb_ + (size_t)rowm * Cc + l31;
        #pragma unroll
        for (int ct = 0; ct < 8; ++ct)
          orow[ct * 32] = acc[ct][r] * wrow[r] + sx[ct * 32];
      }
      if (g == 0) {
        mstat[(s * Bc + b) * Mc + m0 + l31] = Mg;
        lstat[(s * Bc + b) * Mc + m0 + l31] = Lg;
      }
    }
  }
}

// Merge the 4 N-split partials: out = sum_s e^{M_s-Mg} P_s / sum_s e^{M_s-Mg} L_s
__global__ __launch_bounds__(256)
void attn_merge(const float* __restrict__ part, const float* __restrict__ mstat,
                const float* __restrict__ lstat, float* __restrict__ outp)
{
  const int gid = blockIdx.x * 256 + threadIdx.x;   // 16*576*64 threads
  const int c4 = gid & 63;
  const int bm = gid >> 6;
  const float m0 = mstat[bm],         m1 = mstat[9216 + bm],
              m2 = mstat[18432 + bm], m3 = mstat[27648 + bm];
  const float Mg = fmaxf(fmaxf(m0, m1), fmaxf(m2, m3));
  const float w0 = __expf(m0 - Mg), w1 = __expf(m1 - Mg),
              w2 = __expf(m2 - Mg), w3 = __expf(m3 - Mg);
  const float den = w0 * lstat[bm]         + w1 * lstat[9216 + bm]
                  + w2 * lstat[18432 + bm] + w3 * lstat[27648 + bm];
  const float rinv = 1.f / den;
  const size_t o = (size_t)bm * 256 + c4 * 4;
  const float4 a0 = *(const float4*)&part[o];
  const float4 a1 = *(const float4*)&part[2359296 + o];
  const float4 a2 = *(const float4*)&part[4718592 + o];
  const float4 a3 = *(const float4*)&part[7077888 + o];
  float4 r;
  r.x = (w0*a0.x + w1*a1.x + w2*a2.x + w3*a3.x) * rinv;
  r.y = (w0*a0.y + w1*a1.y + w2*a2.y + w3*a3.y) * rinv;
  r.z = (w0*a0.z + w1*a1.z + w2*a2.z + w3*a3.z) * rinv;
  r.w = (w0*a0.w + w1*a1.w + w2*a2.w + w3*a3.w) * rinv;
  *(float4*)&outp[o] = r;
}

extern "C" void kernel_launch(void* const* d_in, const int* in_sizes, int n_in,
                              void* d_out, int out_size, void* d_ws, size_t ws_size,
                              hipStream_t stream)
{
  const float* fm = (const float*)d_in[0];
  const float* fq = (const float*)d_in[1];
  float* out = (float*)d_out;
  const size_t part_elems = (size_t)4 * Bc * Mc * Cc;   // 9,437,184 f32
  const size_t stat_elems = (size_t)4 * Bc * Mc;        // 36,864 f32
  const size_t need = (part_elems + 2 * stat_elems) * sizeof(float);
  if (ws_size >= need) {
    float* part = (float*)d_ws;
    float* mst  = part + part_elems;
    float* lst  = mst + stat_elems;
    attn_main<<<576, 256, 0, stream>>>(fm, fq, part, mst, lst, 4, 18);
    attn_merge<<<2304, 256, 0, stream>>>(part, mst, lst, out);
  } else {
    // ws too small: single split, write d_out directly (144 blocks; slower but correct)
    attn_main<<<144, 256, 0, stream>>>(fm, fq, out, nullptr, nullptr, 1, 72);
  }
}

// Round 2
// 122.534 us; speedup vs baseline: 2.3952x; 2.3952x over previous
//
#include <hip/hip_runtime.h>
#include <hip/hip_bf16.h>

// Flash-attention formulation of memory_fuse:
//   B=16, C=256, N=T*H*W=4608 (kv tokens), M=H*W=576 (q tokens)
//   S[n,m] = sum_c fm[c,n]*fq[c,m]/16 ; attn = softmax_n(S) ; y[m,c] = sum_n fm[c,n]*attn[n,m]
// Round 2: pre-pass converts fm -> bf16 LDS-image blobs (both swizzled layouts);
// main kernel stages via linear global_load_lds (16B) with counted-vmcnt pipeline
// (kT/kN regions ping-pong between QK^T and PV phases; never vmcnt(0) in loop).

#define Bc 16
#define Cc 256
#define Nc 4608
#define Mc 576
#define NTILES 72            // 4608/64 n-tiles per batch
#define TILE_BYTES 65536     // [kT 32KB][kN 32KB] per (b,tile)

typedef short bf16x8 __attribute__((ext_vector_type(8)));
typedef short bf16x4 __attribute__((ext_vector_type(4)));
typedef float f32x16 __attribute__((ext_vector_type(16)));

static __device__ __forceinline__ short f2bf(float f) {
  return __builtin_bit_cast(short, __float2bfloat16(f));   // RNE f32->bf16
}

#define AS1 __attribute__((address_space(1)))
#define AS3 __attribute__((address_space(3)))
static __device__ __forceinline__ void gload16(const char* g, char* l) {
  __builtin_amdgcn_global_load_lds((const AS1 void*)g, (AS3 void*)l, 16, 0, 0);
}

// ---------------------------------------------------------------------------
// Pre-pass: one block per (b, 64n-tile). Stages fm f32 -> bf16 into LDS in the
// two swizzled layouts (verbatim round-1 staging code), then linear-dumps the
// 64KB LDS image to the blob. Main kernel later copies it back linearly.
__global__ __launch_bounds__(256, 2)
void prep_blob(const float* __restrict__ fm, char* __restrict__ blob)
{
  __shared__ __align__(16) char smem[65536];
  short* kT = (short*)smem;
  short* kN = (short*)(smem + 32768);
  const int tile = blockIdx.x;          // 0..1151
  const int b = tile / NTILES, t = tile % NTILES;
  const int tid = threadIdx.x;
  const float* fmb = fm + (size_t)b * Cc * Nc;
  const int nb = t * 64;

  #pragma unroll 2
  for (int i = 0; i < 8; ++i) {
    const int idx = i * 256 + tid;
    const int c   = (idx >> 4) * 2;
    const int n4  = idx & 15;
    const float* src = fmb + (size_t)c * Nc + nb + n4 * 4;
    const float4 va = *(const float4*)src;
    const float4 vb = *(const float4*)(src + Nc);
    bf16x4 sa, sb;
    sa[0]=f2bf(va.x); sa[1]=f2bf(va.y); sa[2]=f2bf(va.z); sa[3]=f2bf(va.w);
    sb[0]=f2bf(vb.x); sb[1]=f2bf(vb.y); sb[2]=f2bf(vb.z); sb[3]=f2bf(vb.w);
    const int bn = n4 >> 1, off = (n4 & 1) * 4;
    *(bf16x4*)&kN[c * 64       + ((bn ^ (c & 7))       << 3) + off] = sa;
    *(bf16x4*)&kN[(c + 1) * 64 + ((bn ^ ((c + 1) & 7)) << 3) + off] = sb;
    const int cb = c >> 3;
    #pragma unroll
    for (int k = 0; k < 4; ++k) {
      const int row = n4 * 4 + k;
      const unsigned pk = (unsigned short)sa[k] | ((unsigned)(unsigned short)sb[k] << 16);
      *(unsigned*)&kT[row * 256 + ((cb ^ (row & 7)) << 3) + (c & 7)] = pk;
    }
  }
  __syncthreads();
  char* dst = blob + (size_t)tile * TILE_BYTES;
  #pragma unroll
  for (int i = 0; i < 16; ++i) {
    const int off = i * 4096 + tid * 16;
    *(float4*)(dst + off) = *(const float4*)(smem + off);
  }
}

// ---------------------------------------------------------------------------
// Main kernel (blob-staged, pipelined). Math identical to verified round-1.
__global__ __launch_bounds__(256, 2)
void attn_main2(const char* __restrict__ blob, const float* __restrict__ fq,
                float* __restrict__ outp, float* __restrict__ mstat,
                float* __restrict__ lstat, const int nsplit, const int nsuper)
{
  __shared__ __align__(16) char smem[77824];
  short* kT  = (short*)smem;
  short* kN  = (short*)(smem + 32768);
  short* pB  = (short*)(smem + 65536);
  float* stm = (float*)(smem + 75776);
  float* stl = (float*)(smem + 76288);
  float* stsc= (float*)(smem + 76800);
  float* stLg= (float*)(smem + 77312);
  float* xch = (float*)smem;

  const int tid  = threadIdx.x;
  const int lane = tid & 63;
  const int l31  = lane & 31;
  const int g    = lane >> 5;
  const int wv   = tid >> 6;
  const int mi   = wv & 1;
  const int ni   = wv >> 1;

  // XCD-clustered remap (grid divisible by 8)
  const int cpx = gridDim.x >> 3;
  const int bid = blockIdx.x;
  const int lid = (bid & 7) * cpx + (bid >> 3);
  const int qt = lid % 9;
  const int bs = lid / 9;
  const int b  = bs & 15;
  const int s  = bs >> 4;
  const int m0 = qt * 64 + mi * 32;

  const char* tb0 = blob + (size_t)(b * NTILES + s * nsuper) * TILE_BYTES;
  char* lT = (char*)smem + wv * 8192;            // this wave's kT quarter
  char* lN = (char*)smem + 32768 + wv * 8192;    // this wave's kN quarter

  // ---- prologue: issue tile 0 (kT then kN), 8 calls each per wave
  {
    const char* gt = tb0;
    #pragma unroll
    for (int j = 0; j < 8; ++j) gload16(gt + wv*8192 + j*1024 + lane*16, lT + j*1024);
    #pragma unroll
    for (int j = 0; j < 8; ++j) gload16(gt + 32768 + wv*8192 + j*1024 + lane*16, lN + j*1024);
  }

  // ---- hoist Q fragments (overlaps with staged loads in flight)
  bf16x8 qf[16];
  {
    const float* fqb = fq + (size_t)b * Cc * Mc + m0 + l31;
    #pragma unroll
    for (int kt = 0; kt < 16; ++kt) {
      bf16x8 q;
      #pragma unroll
      for (int j = 0; j < 8; ++j) {
        const int c = kt * 16 + g * 8 + j;
        q[j] = f2bf(fqb[c * Mc] * 0.0625f);
      }
      qf[kt] = q;
    }
  }

  f32x16 acc[8];
  #pragma unroll
  for (int i = 0; i < 8; ++i)
    #pragma unroll
    for (int e = 0; e < 16; ++e) acc[i][e] = 0.f;
  float mr = -1e30f, lr = 0.f;
  const int tb = ni * 32;

  for (int it = 0; it < nsuper; ++it) {
    const bool more = (it + 1 < nsuper);
    // kT_it ready (kN_it's 8 loads may remain outstanding); publish across waves
    asm volatile("s_waitcnt vmcnt(8)\ns_barrier" ::: "memory");

    // ---- QK^T
    f32x16 sacc;
    #pragma unroll
    for (int e = 0; e < 16; ++e) sacc[e] = 0.f;
    const int nrow = tb + l31;
    const short* kTr = &kT[nrow * 256];
    const int sw = nrow & 7;
    #pragma unroll
    for (int kt = 0; kt < 16; ++kt) {
      const bf16x8 a = *(const bf16x8*)&kTr[((2 * kt + g) ^ sw) << 3];
      sacc = __builtin_amdgcn_mfma_f32_32x32x16_bf16(a, qf[kt], sacc, 0, 0, 0);
    }
    // all waves done reading kT -> safe to overwrite
    asm volatile("s_waitcnt lgkmcnt(0)\ns_barrier" ::: "memory");
    if (more) {
      const char* gt = tb0 + (size_t)(it + 1) * TILE_BYTES;
      #pragma unroll
      for (int j = 0; j < 8; ++j) gload16(gt + wv*8192 + j*1024 + lane*16, lT + j*1024);
    }

    // ---- online softmax (unchanged)
    float pmax = sacc[0];
    #pragma unroll
    for (int r = 1; r < 16; ++r) pmax = fmaxf(pmax, sacc[r]);
    pmax = fmaxf(pmax, __shfl_xor(pmax, 32));

    if (!__all(pmax <= mr + 8.f)) {
      const float mn = fmaxf(mr, pmax);
      const float sc = __expf(mr - mn);
      lr *= sc;
      mr = mn;
      if (g == 0) stsc[wv * 32 + l31] = sc;
      #pragma unroll
      for (int r = 0; r < 16; ++r) {
        const int rowm = (r & 3) + 8 * (r >> 2) + 4 * g;
        const float sr = stsc[wv * 32 + rowm];
        #pragma unroll
        for (int ct = 0; ct < 8; ++ct) acc[ct][r] *= sr;
      }
    }

    float csum = 0.f;
    short* pw_ = &pB[(wv * 32 + l31) * 40];
    #pragma unroll
    for (int q4 = 0; q4 < 4; ++q4) {
      const float e0 = __expf(sacc[q4*4+0] - mr);
      const float e1 = __expf(sacc[q4*4+1] - mr);
      const float e2 = __expf(sacc[q4*4+2] - mr);
      const float e3 = __expf(sacc[q4*4+3] - mr);
      csum += (e0 + e1) + (e2 + e3);
      bf16x4 pk;
      pk[0]=f2bf(e0); pk[1]=f2bf(e1); pk[2]=f2bf(e2); pk[3]=f2bf(e3);
      *(bf16x4*)&pw_[q4 * 8 + g * 4] = pk;
    }
    csum += __shfl_xor(csum, 32);
    lr += csum;

    // kN_it ready (kT_{it+1} loads outstanding if issued)
    if (more) asm volatile("s_waitcnt vmcnt(8)\ns_barrier" ::: "memory");
    else      asm volatile("s_waitcnt vmcnt(0)\ns_barrier" ::: "memory");

    // ---- PV
    const short* pr_ = &pB[(wv * 32 + l31) * 40];
    const bf16x8 pf0 = *(const bf16x8*)&pr_[g * 8];
    const bf16x8 pf1 = *(const bf16x8*)&pr_[16 + g * 8];
    #pragma unroll
    for (int ct = 0; ct < 8; ++ct) {
      const int crow = ct * 32 + l31;
      const short* kNr = &kN[crow * 64];
      const int swc = crow & 7;
      const bf16x8 b0 = *(const bf16x8*)&kNr[((4 * ni + g)     ^ swc) << 3];
      const bf16x8 b1 = *(const bf16x8*)&kNr[((4 * ni + 2 + g) ^ swc) << 3];
      acc[ct] = __builtin_amdgcn_mfma_f32_32x32x16_bf16(pf0, b0, acc[ct], 0, 0, 0);
      acc[ct] = __builtin_amdgcn_mfma_f32_32x32x16_bf16(pf1, b1, acc[ct], 0, 0, 0);
    }
    // all waves done reading kN -> safe to overwrite
    asm volatile("s_waitcnt lgkmcnt(0)\ns_barrier" ::: "memory");
    if (more) {
      const char* gt = tb0 + (size_t)(it + 1) * TILE_BYTES;
      #pragma unroll
      for (int j = 0; j < 8; ++j) gload16(gt + 32768 + wv*8192 + j*1024 + lane*16, lN + j*1024);
    }
  }

  // ---- merge the two n-parity waves, then write out (unchanged)
  __syncthreads();
  if (g == 0) { stm[wv * 32 + l31] = mr; stl[wv * 32 + l31] = lr; }
  __syncthreads();
  const int pwv = wv ^ 2;
  const float mo = stm[pwv * 32 + l31];
  const float lo = stl[pwv * 32 + l31];
  const float Mg  = fmaxf(mr, mo);
  const float wsf = __expf(mr - Mg);
  const float Lg  = wsf * lr + __expf(mo - Mg) * lo;
  if (g == 0) { stsc[wv * 32 + l31] = wsf; stLg[wv * 32 + l31] = Lg; }

  float wrow[16], Lrow[16];
  #pragma unroll
  for (int r = 0; r < 16; ++r) {
    const int rowm = (r & 3) + 8 * (r >> 2) + 4 * g;
    wrow[r] = stsc[wv * 32 + rowm];
    Lrow[r] = stLg[wv * 32 + rowm];
  }
  if (ni == 1) {
    #pragma unroll
    for (int r = 0; r < 16; ++r) {
      const int rowm = (r & 3) + 8 * (r >> 2) + 4 * g;
      float* dst = &xch[(mi * 32 + rowm) * 256 + l31];
      #pragma unroll
      for (int ct = 0; ct < 8; ++ct) dst[ct * 32] = acc[ct][r] * wrow[r];
    }
  }
  __syncthreads();
  if (ni == 0) {
    if (nsplit == 1) {
      float* ob = outp + ((size_t)b * Mc + m0) * Cc;
      #pragma unroll
      for (int r = 0; r < 16; ++r) {
        const int rowm = (r & 3) + 8 * (r >> 2) + 4 * g;
        const float* sx = &xch[(mi * 32 + rowm) * 256 + l31];
        const float rinv = 1.f / Lrow[r];
        float* orow = ob + (size_t)rowm * Cc + l31;
        #pragma unroll
        for (int ct = 0; ct < 8; ++ct)
          orow[ct * 32] = (acc[ct][r] * wrow[r] + sx[ct * 32]) * rinv;
      }
    } else {
      float* pb_ = outp + ((size_t)(s * Bc + b) * Mc + m0) * Cc;
      #pragma unroll
      for (int r = 0; r < 16; ++r) {
        const int rowm = (r & 3) + 8 * (r >> 2) + 4 * g;
        const float* sx = &xch[(mi * 32 + rowm) * 256 + l31];
        float* orow = pb_ + (size_t)rowm * Cc + l31;
        #pragma unroll
        for (int ct = 0; ct < 8; ++ct)
          orow[ct * 32] = acc[ct][r] * wrow[r] + sx[ct * 32];
      }
      if (g == 0) {
        mstat[(s * Bc + b) * Mc + m0 + l31] = Mg;
        lstat[(s * Bc + b) * Mc + m0 + l31] = Lg;
      }
    }
  }
}

// ---------------------------------------------------------------------------
// Legacy (round-1) kernel, kept as ws-size fallback.
__global__ __launch_bounds__(256, 2)
void attn_main(const float* __restrict__ fm, const float* __restrict__ fq,
               float* __restrict__ outp, float* __restrict__ mstat,
               float* __restrict__ lstat, const int nsplit, const int nsuper)
{
  __shared__ __align__(16) char smem[77824];
  short* kT  = (short*)smem;
  short* kN  = (short*)(smem + 32768);
  short* pB  = (short*)(smem + 65536);
  float* stm = (float*)(smem + 75776);
  float* stl = (float*)(smem + 76288);
  float* stsc= (float*)(smem + 76800);
  float* stLg= (float*)(smem + 77312);
  float* xch = (float*)smem;

  const int tid  = threadIdx.x;
  const int lane = tid & 63;
  const int l31  = lane & 31;
  const int g    = lane >> 5;
  const int wv   = tid >> 6;
  const int mi   = wv & 1;
  const int ni   = wv >> 1;

  const int nblk = gridDim.x;
  const int cpx  = nblk >> 3;
  const int bid  = blockIdx.x;
  const int lid  = (bid & 7) * cpx + (bid >> 3);
  const int qt = lid % 9;
  const int bs = lid / 9;
  const int b  = bs & 15;
  const int s  = bs >> 4;

  const int m0 = qt * 64 + mi * 32;
  const int n0 = s * (Nc / nsplit);

  bf16x8 qf[16];
  {
    const float* fqb = fq + (size_t)b * Cc * Mc + m0 + l31;
    #pragma unroll
    for (int kt = 0; kt < 16; ++kt) {
      bf16x8 q;
      #pragma unroll
      for (int j = 0; j < 8; ++j) {
        const int c = kt * 16 + g * 8 + j;
        q[j] = f2bf(fqb[c * Mc] * 0.0625f);
      }
      qf[kt] = q;
    }
  }

  f32x16 acc[8];
  #pragma unroll
  for (int i = 0; i < 8; ++i)
    #pragma unroll
    for (int e = 0; e < 16; ++e) acc[i][e] = 0.f;
  float mr = -1e30f, lr = 0.f;

  const float* fmb = fm + (size_t)b * Cc * Nc;
  const int tb = ni * 32;

  for (int it = 0; it < nsuper; ++it) {
    const int nb = n0 + it * 64;
    __syncthreads();
    #pragma unroll 2
    for (int i = 0; i < 8; ++i) {
      const int idx = i * 256 + tid;
      const int c   = (idx >> 4) * 2;
      const int n4  = idx & 15;
      const float* src = fmb + (size_t)c * Nc + nb + n4 * 4;
      const float4 va = *(const float4*)src;
      const float4 vb = *(const float4*)(src + Nc);
      bf16x4 sa, sb;
      sa[0]=f2bf(va.x); sa[1]=f2bf(va.y); sa[2]=f2bf(va.z); sa[3]=f2bf(va.w);
      sb[0]=f2bf(vb.x); sb[1]=f2bf(vb.y); sb[2]=f2bf(vb.z); sb[3]=f2bf(vb.w);
      const int bn = n4 >> 1, off = (n4 & 1) * 4;
      *(bf16x4*)&kN[c * 64       + ((bn ^ (c & 7))       << 3) + off] = sa;
      *(bf16x4*)&kN[(c + 1) * 64 + ((bn ^ ((c + 1) & 7)) << 3) + off] = sb;
      const int cb = c >> 3;
      #pragma unroll
      for (int k = 0; k < 4; ++k) {
        const int row = n4 * 4 + k;
        const unsigned pk = (unsigned short)sa[k] | ((unsigned)(unsigned short)sb[k] << 16);
        *(unsigned*)&kT[row * 256 + ((cb ^ (row & 7)) << 3) + (c & 7)] = pk;
      }
    }
    __syncthreads();

    f32x16 sacc;
    #pragma unroll
    for (int e = 0; e < 16; ++e) sacc[e] = 0.f;
    const int nrow = tb + l31;
    const short* kTr = &kT[nrow * 256];
    const int sw = nrow & 7;
    #pragma unroll
    for (int kt = 0; kt < 16; ++kt) {
      const bf16x8 a = *(const bf16x8*)&kTr[((2 * kt + g) ^ sw) << 3];
      sacc = __builtin_amdgcn_mfma_f32_32x32x16_bf16(a, qf[kt], sacc, 0, 0, 0);
    }

    float pmax = sacc[0];
    #pragma unroll
    for (int r = 1; r < 16; ++r) pmax = fmaxf(pmax, sacc[r]);
    pmax = fmaxf(pmax, __shfl_xor(pmax, 32));

    if (!__all(pmax <= mr + 8.f)) {
      const float mn = fmaxf(mr, pmax);
      const float sc = __expf(mr - mn);
      lr *= sc;
      mr = mn;
      if (g == 0) stsc[wv * 32 + l31] = sc;
      #pragma unroll
      for (int r = 0; r < 16; ++r) {
        const int rowm = (r & 3) + 8 * (r >> 2) + 4 * g;
        const float sr = stsc[wv * 32 + rowm];
        #pragma unroll
        for (int ct = 0; ct < 8; ++ct) acc[ct][r] *= sr;
      }
    }

    float csum = 0.f;
    short* pw_ = &pB[(wv * 32 + l31) * 40];
    #pragma unroll
    for (int q4 = 0; q4 < 4; ++q4) {
      const float e0 = __expf(sacc[q4*4+0] - mr);
      const float e1 = __expf(sacc[q4*4+1] - mr);
      const float e2 = __expf(sacc[q4*4+2] - mr);
      const float e3 = __expf(sacc[q4*4+3] - mr);
      csum += (e0 + e1) + (e2 + e3);
      bf16x4 pk;
      pk[0]=f2bf(e0); pk[1]=f2bf(e1); pk[2]=f2bf(e2); pk[3]=f2bf(e3);
      *(bf16x4*)&pw_[q4 * 8 + g * 4] = pk;
    }
    csum += __shfl_xor(csum, 32);
    lr += csum;

    const short* pr_ = &pB[(wv * 32 + l31) * 40];
    const bf16x8 pf0 = *(const bf16x8*)&pr_[g * 8];
    const bf16x8 pf1 = *(const bf16x8*)&pr_[16 + g * 8];
    #pragma unroll
    for (int ct = 0; ct < 8; ++ct) {
      const int crow = ct * 32 + l31;
      const short* kNr = &kN[crow * 64];
      const int swc = crow & 7;
      const bf16x8 b0 = *(const bf16x8*)&kNr[((4 * ni + g)     ^ swc) << 3];
      const bf16x8 b1 = *(const bf16x8*)&kNr[((4 * ni + 2 + g) ^ swc) << 3];
      acc[ct] = __builtin_amdgcn_mfma_f32_32x32x16_bf16(pf0, b0, acc[ct], 0, 0, 0);
      acc[ct] = __builtin_amdgcn_mfma_f32_32x32x16_bf16(pf1, b1, acc[ct], 0, 0, 0);
    }
  }

  __syncthreads();
  if (g == 0) { stm[wv * 32 + l31] = mr; stl[wv * 32 + l31] = lr; }
  __syncthreads();
  const int pwv = wv ^ 2;
  const float mo = stm[pwv * 32 + l31];
  const float lo = stl[pwv * 32 + l31];
  const float Mg  = fmaxf(mr, mo);
  const float wsf = __expf(mr - Mg);
  const float Lg  = wsf * lr + __expf(mo - Mg) * lo;
  if (g == 0) { stsc[wv * 32 + l31] = wsf; stLg[wv * 32 + l31] = Lg; }

  float wrow[16], Lrow[16];
  #pragma unroll
  for (int r = 0; r < 16; ++r) {
    const int rowm = (r & 3) + 8 * (r >> 2) + 4 * g;
    wrow[r] = stsc[wv * 32 + rowm];
    Lrow[r] = stLg[wv * 32 + rowm];
  }
  if (ni == 1) {
    #pragma unroll
    for (int r = 0; r < 16; ++r) {
      const int rowm = (r & 3) + 8 * (r >> 2) + 4 * g;
      float* dst = &xch[(mi * 32 + rowm) * 256 + l31];
      #pragma unroll
      for (int ct = 0; ct < 8; ++ct) dst[ct * 32] = acc[ct][r] * wrow[r];
    }
  }
  __syncthreads();
  if (ni == 0) {
    if (nsplit == 1) {
      float* ob = outp + ((size_t)b * Mc + m0) * Cc;
      #pragma unroll
      for (int r = 0; r < 16; ++r) {
        const int rowm = (r & 3) + 8 * (r >> 2) + 4 * g;
        const float* sx = &xch[(mi * 32 + rowm) * 256 + l31];
        const float rinv = 1.f / Lrow[r];
        float* orow = ob + (size_t)rowm * Cc + l31;
        #pragma unroll
        for (int ct = 0; ct < 8; ++ct)
          orow[ct * 32] = (acc[ct][r] * wrow[r] + sx[ct * 32]) * rinv;
      }
    } else {
      float* pb_ = outp + ((size_t)(s * Bc + b) * Mc + m0) * Cc;
      #pragma unroll
      for (int r = 0; r < 16; ++r) {
        const int rowm = (r & 3) + 8 * (r >> 2) + 4 * g;
        const float* sx = &xch[(mi * 32 + rowm) * 256 + l31];
        float* orow = pb_ + (size_t)rowm * Cc + l31;
        #pragma unroll
        for (int ct = 0; ct < 8; ++ct)
          orow[ct * 32] = acc[ct][r] * wrow[r] + sx[ct * 32];
      }
      if (g == 0) {
        mstat[(s * Bc + b) * Mc + m0 + l31] = Mg;
        lstat[(s * Bc + b) * Mc + m0 + l31] = Lg;
      }
    }
  }
}

// Merge the 4 N-split partials.
__global__ __launch_bounds__(256)
void attn_merge(const float* __restrict__ part, const float* __restrict__ mstat,
                const float* __restrict__ lstat, float* __restrict__ outp)
{
  const int gid = blockIdx.x * 256 + threadIdx.x;
  const int c4 = gid & 63;
  const int bm = gid >> 6;
  const float m0 = mstat[bm],         m1 = mstat[9216 + bm],
              m2 = mstat[18432 + bm], m3 = mstat[27648 + bm];
  const float Mg = fmaxf(fmaxf(m0, m1), fmaxf(m2, m3));
  const float w0 = __expf(m0 - Mg), w1 = __expf(m1 - Mg),
              w2 = __expf(m2 - Mg), w3 = __expf(m3 - Mg);
  const float den = w0 * lstat[bm]         + w1 * lstat[9216 + bm]
                  + w2 * lstat[18432 + bm] + w3 * lstat[27648 + bm];
  const float rinv = 1.f / den;
  const size_t o = (size_t)bm * 256 + c4 * 4;
  const float4 a0 = *(const float4*)&part[o];
  const float4 a1 = *(const float4*)&part[2359296 + o];
  const float4 a2 = *(const float4*)&part[4718592 + o];
  const float4 a3 = *(const float4*)&part[7077888 + o];
  float4 r;
  r.x = (w0*a0.x + w1*a1.x + w2*a2.x + w3*a3.x) * rinv;
  r.y = (w0*a0.y + w1*a1.y + w2*a2.y + w3*a3.y) * rinv;
  r.z = (w0*a0.z + w1*a1.z + w2*a2.z + w3*a3.z) * rinv;
  r.w = (w0*a0.w + w1*a1.w + w2*a2.w + w3*a3.w) * rinv;
  *(float4*)&outp[o] = r;
}

extern "C" void kernel_launch(void* const* d_in, const int* in_sizes, int n_in,
                              void* d_out, int out_size, void* d_ws, size_t ws_size,
                              hipStream_t stream)
{
  const float* fm = (const float*)d_in[0];
  const float* fq = (const float*)d_in[1];
  float* out = (float*)d_out;

  const size_t blob_bytes = (size_t)Bc * NTILES * TILE_BYTES;   // 75,497,472
  const size_t part_elems = (size_t)4 * Bc * Mc * Cc;           // 9,437,184 f32
  const size_t stat_elems = (size_t)4 * Bc * Mc;                // 36,864 f32
  const size_t need_full   = blob_bytes + (part_elems + 2 * stat_elems) * sizeof(float);
  const size_t need_blob1  = blob_bytes;                        // 1-split blob path
  const size_t need_legacy = (part_elems + 2 * stat_elems) * sizeof(float);

  if (ws_size >= need_full) {
    char* blob = (char*)d_ws;
    float* part = (float*)(blob + blob_bytes);
    float* mst  = part + part_elems;
    float* lst  = mst + stat_elems;
    prep_blob<<<Bc * NTILES, 256, 0, stream>>>(fm, blob);
    attn_main2<<<576, 256, 0, stream>>>(blob, fq, part, mst, lst, 4, 18);
    attn_merge<<<2304, 256, 0, stream>>>(part, mst, lst, out);
  } else if (ws_size >= need_blob1) {
    char* blob = (char*)d_ws;
    prep_blob<<<Bc * NTILES, 256, 0, stream>>>(fm, blob);
    attn_main2<<<144, 256, 0, stream>>>(blob, fq, out, nullptr, nullptr, 1, 72);
  } else if (ws_size >= need_legacy) {
    float* part = (float*)d_ws;
    float* mst  = part + part_elems;
    float* lst  = mst + stat_elems;
    attn_main<<<576, 256, 0, stream>>>(fm, fq, part, mst, lst, 4, 18);
    attn_merge<<<2304, 256, 0, stream>>>(part, mst, lst, out);
  } else {
    attn_main<<<144, 256, 0, stream>>>(fm, fq, out, nullptr, nullptr, 1, 72);
  }
}

// Round 3
// 103.762 us; speedup vs baseline: 2.8286x; 1.1809x over previous
//
#include <hip/hip_runtime.h>
#include <hip/hip_bf16.h>

// Flash-attention formulation of memory_fuse:
//   B=16, C=256, N=4608, M=576
//   S = fm^T fq /16 ; attn = softmax_n ; y[b,m,c] = sum_n fm[c,n] attn[n,m]
// Round 3: M=128 blocks (4 m-waves), in-register P redistribution via
// cvt_pk_bf16 + permlane32_swap (no P LDS round-trip), exp2-folded softmax,
// nsplit=6 with f16 partials. Blob staging (bf16, both swizzled layouts) kept
// verbatim from verified round-2 prep_blob.

#define Bc 16
#define Cc 256
#define Nc 4608
#define Mc 576
#define NTILES 72            // 4608/64 n-tiles per batch
#define TILE_BYTES 65536     // [kT 32KB][kN 32KB] per (b,tile)
#define NSPLIT 6
#define NSUPER 12            // 72/6
#define PART_STRIDE 2359296  // 16*576*256 elems per split
#define STAT_STRIDE 9216     // 16*576
#define RESCALE_THR2 7.2f    // ~5 nats in exp2 units

typedef short bf16x8 __attribute__((ext_vector_type(8)));
typedef short bf16x4 __attribute__((ext_vector_type(4)));
typedef float f32x16 __attribute__((ext_vector_type(16)));
typedef unsigned u32x4 __attribute__((ext_vector_type(4)));
typedef _Float16 f16x4 __attribute__((ext_vector_type(4)));

static __device__ __forceinline__ short f2bf(float f) {
  return __builtin_bit_cast(short, __float2bfloat16(f));   // RNE f32->bf16
}
static __device__ __forceinline__ unsigned cvtpk(float lo, float hi) {
  unsigned d;
  asm("v_cvt_pk_bf16_f32 %0, %1, %2" : "=v"(d) : "v"(lo), "v"(hi));
  return d;
}

#define AS1 __attribute__((address_space(1)))
#define AS3 __attribute__((address_space(3)))
static __device__ __forceinline__ void gload16(const char* g, char* l) {
  __builtin_amdgcn_global_load_lds((const AS1 void*)g, (AS3 void*)l, 16, 0, 0);
}

// ---------------------------------------------------------------------------
// Pre-pass (verbatim round-2, verified): fm f32 -> bf16 LDS-image blobs in the
// two swizzled layouts, linear-dumped 64KB per (b, 64n-tile).
__global__ __launch_bounds__(256, 2)
void prep_blob(const float* __restrict__ fm, char* __restrict__ blob)
{
  __shared__ __align__(16) char smem[65536];
  short* kT = (short*)smem;
  short* kN = (short*)(smem + 32768);
  const int tile = blockIdx.x;          // 0..1151
  const int b = tile / NTILES, t = tile % NTILES;
  const int tid = threadIdx.x;
  const float* fmb = fm + (size_t)b * Cc * Nc;
  const int nb = t * 64;

  #pragma unroll 2
  for (int i = 0; i < 8; ++i) {
    const int idx = i * 256 + tid;
    const int c   = (idx >> 4) * 2;
    const int n4  = idx & 15;
    const float* src = fmb + (size_t)c * Nc + nb + n4 * 4;
    const float4 va = *(const float4*)src;
    const float4 vb = *(const float4*)(src + Nc);
    bf16x4 sa, sb;
    sa[0]=f2bf(va.x); sa[1]=f2bf(va.y); sa[2]=f2bf(va.z); sa[3]=f2bf(va.w);
    sb[0]=f2bf(vb.x); sb[1]=f2bf(vb.y); sb[2]=f2bf(vb.z); sb[3]=f2bf(vb.w);
    const int bn = n4 >> 1, off = (n4 & 1) * 4;
    *(bf16x4*)&kN[c * 64       + ((bn ^ (c & 7))       << 3) + off] = sa;
    *(bf16x4*)&kN[(c + 1) * 64 + ((bn ^ ((c + 1) & 7)) << 3) + off] = sb;
    const int cb = c >> 3;
    #pragma unroll
    for (int k = 0; k < 4; ++k) {
      const int row = n4 * 4 + k;
      const unsigned pk = (unsigned short)sa[k] | ((unsigned)(unsigned short)sb[k] << 16);
      *(unsigned*)&kT[row * 256 + ((cb ^ (row & 7)) << 3) + (c & 7)] = pk;
    }
  }
  __syncthreads();
  char* dst = blob + (size_t)tile * TILE_BYTES;
  #pragma unroll
  for (int i = 0; i < 16; ++i) {
    const int off = i * 4096 + tid * 16;
    *(float4*)(dst + off) = *(const float4*)(smem + off);
  }
}

// ---------------------------------------------------------------------------
// Main kernel v3: block = 4 m-waves (M=128), shared 64n tile, counted-vmcnt
// ping-pong, in-register P->PA redistribution (T12).
__global__ __launch_bounds__(256, 2)
void attn_main3(const char* __restrict__ blob, const float* __restrict__ fq,
                float* __restrict__ outp, _Float16* __restrict__ part,
                float* __restrict__ mstat, float* __restrict__ lstat,
                const int nsplit, const int nsuper)
{
  __shared__ __align__(16) char smem[67072];
  short* kT  = (short*)smem;                 // [64 n][256 c], 16B-swz by (n&7)
  short* kN  = (short*)(smem + 32768);       // [256 c][64 n], 16B-swz by (c&7)
  float* stsc= (float*)(smem + 65536);       // [4][32] rescale broadcast
  float* stLg= (float*)(smem + 66048);       // [4][32] L broadcast
  float* stm = (float*)(smem + 66560);       // [4][32] m broadcast

  const int tid  = threadIdx.x;
  const int lane = tid & 63;
  const int l31  = lane & 31;
  const int g    = lane >> 5;
  const int wv   = tid >> 6;

  // XCD-clustered remap: consecutive lids share one (b,s) fm slice.
  const int cpx = gridDim.x >> 3;
  const int bid = blockIdx.x;
  const int lid = (bid & 7) * cpx + (bid >> 3);
  const int mb    = lid % 5;
  const int slice = lid / 5;
  const int b = slice & 15;
  const int s = slice >> 4;

  const int mw = mb * 128 + wv * 32;
  const bool valid = (mw < Mc);
  const int m0 = valid ? mw : (Mc - 64 + (wv & 1) * 32);

  const char* tb0 = blob + (size_t)(b * NTILES + s * nsuper) * TILE_BYTES;
  char* lT = (char*)smem + wv * 8192;
  char* lN = (char*)smem + 32768 + wv * 8192;

  // prologue: issue tile 0 (kT then kN), 8 gloads each per wave
  {
    const char* gt = tb0;
    #pragma unroll
    for (int j = 0; j < 8; ++j) gload16(gt + wv*8192 + j*1024 + lane*16, lT + j*1024);
    #pragma unroll
    for (int j = 0; j < 8; ++j) gload16(gt + 32768 + wv*8192 + j*1024 + lane*16, lN + j*1024);
  }

  // Q fragments, scale = (1/16)*log2(e) folded (softmax in exp2 domain)
  bf16x8 qf[16];
  {
    const float* fqb = fq + (size_t)b * Cc * Mc + m0 + l31;
    #pragma unroll
    for (int kt = 0; kt < 16; ++kt) {
      bf16x8 q;
      #pragma unroll
      for (int j = 0; j < 8; ++j) {
        const int c = kt * 16 + g * 8 + j;
        q[j] = f2bf(fqb[c * Mc] * 0.09016844f);
      }
      qf[kt] = q;
    }
  }

  f32x16 acc[8];
  #pragma unroll
  for (int i = 0; i < 8; ++i)
    #pragma unroll
    for (int e = 0; e < 16; ++e) acc[i][e] = 0.f;
  float m2r = -1e30f, lr = 0.f;     // exp2-domain running max / denom (m = m0+l31)
  u32x4 paw[4];                     // PA fragments (4 k-steps of the 64-n tile)

  for (int it = 0; it < nsuper; ++it) {
    const bool more = (it + 1 < nsuper);
    asm volatile("s_waitcnt vmcnt(8)\ns_barrier" ::: "memory");   // kT ready

    #pragma unroll
    for (int sub = 0; sub < 2; ++sub) {
      // ---- QK^T subtile: S[n(32) x m(32)], A = kT rows sub*32+l31
      f32x16 sacc;
      #pragma unroll
      for (int e = 0; e < 16; ++e) sacc[e] = 0.f;
      const short* kTr = &kT[(sub * 32 + l31) * 256];
      const int sw = l31 & 7;
      __builtin_amdgcn_s_setprio(1);
      #pragma unroll
      for (int kt = 0; kt < 16; ++kt) {
        const bf16x8 a = *(const bf16x8*)&kTr[((2 * kt + g) ^ sw) << 3];
        sacc = __builtin_amdgcn_mfma_f32_32x32x16_bf16(a, qf[kt], sacc, 0, 0, 0);
      }
      __builtin_amdgcn_s_setprio(0);

      // ---- online softmax (exp2 domain), lane owns column m = m0+l31
      float pmax = sacc[0];
      #pragma unroll
      for (int r = 1; r < 16; ++r) pmax = fmaxf(pmax, sacc[r]);
      pmax = fmaxf(pmax, __shfl_xor(pmax, 32));

      if (!__all(pmax <= m2r + RESCALE_THR2)) {
        const float mn = fmaxf(m2r, pmax);
        const float sc = exp2f(m2r - mn);
        lr *= sc;
        m2r = mn;
        if (g == 0) stsc[wv * 32 + l31] = sc;
        #pragma unroll
        for (int r = 0; r < 16; ++r) {
          const int rowm = (r & 3) + 8 * (r >> 2) + 4 * g;
          const float sr = stsc[wv * 32 + rowm];
          #pragma unroll
          for (int ct = 0; ct < 8; ++ct) acc[ct][r] *= sr;
        }
      }

      float csum = 0.f;
      #pragma unroll
      for (int r = 0; r < 16; ++r) {
        sacc[r] = exp2f(sacc[r] - m2r);
        csum += sacc[r];
      }
      csum += __shfl_xor(csum, 32);
      lr += csum;

      // ---- P (lane-local, n over regs) -> PA fragments via cvt_pk + permlane32_swap
      // paw[2*sub+ks].word[w] = bf16 pair P[m][n0=16ks+8g+2w], P[m][n0+1]
      #pragma unroll
      for (int ks = 0; ks < 2; ++ks) {
        unsigned w0 = cvtpk(sacc[8*ks+0], sacc[8*ks+1]);
        unsigned w2 = cvtpk(sacc[8*ks+4], sacc[8*ks+5]);
        asm("v_permlane32_swap_b32 %0, %1" : "+v"(w0), "+v"(w2));
        unsigned w1 = cvtpk(sacc[8*ks+2], sacc[8*ks+3]);
        unsigned w3 = cvtpk(sacc[8*ks+6], sacc[8*ks+7]);
        asm("v_permlane32_swap_b32 %0, %1" : "+v"(w1), "+v"(w3));
        u32x4 w; w[0] = w0; w[1] = w1; w[2] = w2; w[3] = w3;
        paw[2*sub + ks] = w;
      }
    }

    // kT consumed by all waves -> refill
    asm volatile("s_waitcnt lgkmcnt(0)\ns_barrier" ::: "memory");
    if (more) {
      const char* gt = tb0 + (size_t)(it + 1) * TILE_BYTES;
      #pragma unroll
      for (int j = 0; j < 8; ++j) gload16(gt + wv*8192 + j*1024 + lane*16, lT + j*1024);
    }

    // kN ready (kT' loads outstanding if issued)
    if (more) asm volatile("s_waitcnt vmcnt(8)\ns_barrier" ::: "memory");
    else      asm volatile("s_waitcnt vmcnt(0)\ns_barrier" ::: "memory");

    // ---- PV: acc[m][c] += P(A, in-register) * fm(B from kN), 4 k-steps
    __builtin_amdgcn_s_setprio(1);
    #pragma unroll
    for (int ct = 0; ct < 8; ++ct) {
      const int crow = ct * 32 + l31;
      const short* kNr = &kN[crow * 64];
      const int swc = crow & 7;
      #pragma unroll
      for (int ks = 0; ks < 4; ++ks) {
        const bf16x8 bv = *(const bf16x8*)&kNr[((ks * 2 + g) ^ swc) << 3];
        acc[ct] = __builtin_amdgcn_mfma_f32_32x32x16_bf16(
            __builtin_bit_cast(bf16x8, paw[ks]), bv, acc[ct], 0, 0, 0);
      }
    }
    __builtin_amdgcn_s_setprio(0);

    // kN consumed -> refill
    asm volatile("s_waitcnt lgkmcnt(0)\ns_barrier" ::: "memory");
    if (more) {
      const char* gt = tb0 + (size_t)(it + 1) * TILE_BYTES;
      #pragma unroll
      for (int j = 0; j < 8; ++j) gload16(gt + 32768 + wv*8192 + j*1024 + lane*16, lN + j*1024);
    }
  }

  // ---- epilogue: broadcast per-m stats to acc rows (wave-private LDS rows)
  if (g == 0) { stLg[wv * 32 + l31] = lr; stm[wv * 32 + l31] = m2r; }

  if (nsplit == 1) {
    if (valid) {
      float* ob = outp + ((size_t)b * Mc + m0) * Cc + l31;
      #pragma unroll
      for (int r = 0; r < 16; ++r) {
        const int rowm = (r & 3) + 8 * (r >> 2) + 4 * g;
        const float rinv = 1.f / stLg[wv * 32 + rowm];
        #pragma unroll
        for (int ct = 0; ct < 8; ++ct)
          ob[(size_t)rowm * Cc + ct * 32] = acc[ct][r] * rinv;
      }
    }
  } else {
    if (valid) {
      _Float16* pb_ = part + (size_t)s * PART_STRIDE + ((size_t)b * Mc + m0) * Cc + l31;
      #pragma unroll
      for (int r = 0; r < 16; ++r) {
        const int rowm = (r & 3) + 8 * (r >> 2) + 4 * g;
        #pragma unroll
        for (int ct = 0; ct < 8; ++ct)
          pb_[(size_t)rowm * Cc + ct * 32] = (_Float16)acc[ct][r];
      }
      if (g == 0) {
        mstat[s * STAT_STRIDE + b * Mc + m0 + l31] = m2r;
        lstat[s * STAT_STRIDE + b * Mc + m0 + l31] = lr;
      }
    }
  }
}

// ---------------------------------------------------------------------------
// Merge the 6 N-split f16 partials (exp2-domain stats).
__global__ __launch_bounds__(256)
void attn_merge6(const _Float16* __restrict__ part, const float* __restrict__ mstat,
                 const float* __restrict__ lstat, float* __restrict__ outp)
{
  const int gid = blockIdx.x * 256 + threadIdx.x;   // 589824 threads
  const int c4 = gid & 63;
  const int bm = gid >> 6;
  float m[NSPLIT];
  float Mg = -1e30f;
  #pragma unroll
  for (int s = 0; s < NSPLIT; ++s) { m[s] = mstat[s * STAT_STRIDE + bm]; Mg = fmaxf(Mg, m[s]); }
  float w[NSPLIT], den = 0.f;
  #pragma unroll
  for (int s = 0; s < NSPLIT; ++s) {
    w[s] = exp2f(m[s] - Mg);
    den += w[s] * lstat[s * STAT_STRIDE + bm];
  }
  const float rinv = 1.f / den;
  const size_t o = (size_t)bm * 256 + c4 * 4;
  float r0 = 0.f, r1 = 0.f, r2 = 0.f, r3 = 0.f;
  #pragma unroll
  for (int s = 0; s < NSPLIT; ++s) {
    const f16x4 a = *(const f16x4*)&part[(size_t)s * PART_STRIDE + o];
    r0 += w[s] * (float)a[0];
    r1 += w[s] * (float)a[1];
    r2 += w[s] * (float)a[2];
    r3 += w[s] * (float)a[3];
  }
  float4 r;
  r.x = r0 * rinv; r.y = r1 * rinv; r.z = r2 * rinv; r.w = r3 * rinv;
  *(float4*)&outp[o] = r;
}

// ---------------------------------------------------------------------------
// Legacy (round-1, verified) single-split kernel — tiny-ws fallback only.
__global__ __launch_bounds__(256, 2)
void attn_main(const float* __restrict__ fm, const float* __restrict__ fq,
               float* __restrict__ outp, float* __restrict__ mstat,
               float* __restrict__ lstat, const int nsplit, const int nsuper)
{
  __shared__ __align__(16) char smem[77824];
  short* kT  = (short*)smem;
  short* kN  = (short*)(smem + 32768);
  short* pB  = (short*)(smem + 65536);
  float* stm = (float*)(smem + 75776);
  float* stl = (float*)(smem + 76288);
  float* stsc= (float*)(smem + 76800);
  float* stLg= (float*)(smem + 77312);
  float* xch = (float*)smem;

  const int tid  = threadIdx.x;
  const int lane = tid & 63;
  const int l31  = lane & 31;
  const int g    = lane >> 5;
  const int wv   = tid >> 6;
  const int mi   = wv & 1;
  const int ni   = wv >> 1;

  const int nblk = gridDim.x;
  const int cpx  = nblk >> 3;
  const int bid  = blockIdx.x;
  const int lid  = (bid & 7) * cpx + (bid >> 3);
  const int qt = lid % 9;
  const int bs = lid / 9;
  const int b  = bs & 15;
  const int s  = bs >> 4;

  const int m0 = qt * 64 + mi * 32;
  const int n0 = s * (Nc / nsplit);

  bf16x8 qf[16];
  {
    const float* fqb = fq + (size_t)b * Cc * Mc + m0 + l31;
    #pragma unroll
    for (int kt = 0; kt < 16; ++kt) {
      bf16x8 q;
      #pragma unroll
      for (int j = 0; j < 8; ++j) {
        const int c = kt * 16 + g * 8 + j;
        q[j] = f2bf(fqb[c * Mc] * 0.0625f);
      }
      qf[kt] = q;
    }
  }

  f32x16 acc[8];
  #pragma unroll
  for (int i = 0; i < 8; ++i)
    #pragma unroll
    for (int e = 0; e < 16; ++e) acc[i][e] = 0.f;
  float mr = -1e30f, lr = 0.f;

  const float* fmb = fm + (size_t)b * Cc * Nc;
  const int tb = ni * 32;

  for (int it = 0; it < nsuper; ++it) {
    const int nb = n0 + it * 64;
    __syncthreads();
    #pragma unroll 2
    for (int i = 0; i < 8; ++i) {
      const int idx = i * 256 + tid;
      const int c   = (idx >> 4) * 2;
      const int n4  = idx & 15;
      const float* src = fmb + (size_t)c * Nc + nb + n4 * 4;
      const float4 va = *(const float4*)src;
      const float4 vb = *(const float4*)(src + Nc);
      bf16x4 sa, sb;
      sa[0]=f2bf(va.x); sa[1]=f2bf(va.y); sa[2]=f2bf(va.z); sa[3]=f2bf(va.w);
      sb[0]=f2bf(vb.x); sb[1]=f2bf(vb.y); sb[2]=f2bf(vb.z); sb[3]=f2bf(vb.w);
      const int bn = n4 >> 1, off = (n4 & 1) * 4;
      *(bf16x4*)&kN[c * 64       + ((bn ^ (c & 7))       << 3) + off] = sa;
      *(bf16x4*)&kN[(c + 1) * 64 + ((bn ^ ((c + 1) & 7)) << 3) + off] = sb;
      const int cb = c >> 3;
      #pragma unroll
      for (int k = 0; k < 4; ++k) {
        const int row = n4 * 4 + k;
        const unsigned pk = (unsigned short)sa[k] | ((unsigned)(unsigned short)sb[k] << 16);
        *(unsigned*)&kT[row * 256 + ((cb ^ (row & 7)) << 3) + (c & 7)] = pk;
      }
    }
    __syncthreads();

    f32x16 sacc;
    #pragma unroll
    for (int e = 0; e < 16; ++e) sacc[e] = 0.f;
    const int nrow = tb + l31;
    const short* kTr = &kT[nrow * 256];
    const int sw = nrow & 7;
    #pragma unroll
    for (int kt = 0; kt < 16; ++kt) {
      const bf16x8 a = *(const bf16x8*)&kTr[((2 * kt + g) ^ sw) << 3];
      sacc = __builtin_amdgcn_mfma_f32_32x32x16_bf16(a, qf[kt], sacc, 0, 0, 0);
    }

    float pmax = sacc[0];
    #pragma unroll
    for (int r = 1; r < 16; ++r) pmax = fmaxf(pmax, sacc[r]);
    pmax = fmaxf(pmax, __shfl_xor(pmax, 32));

    if (!__all(pmax <= mr + 8.f)) {
      const float mn = fmaxf(mr, pmax);
      const float sc = __expf(mr - mn);
      lr *= sc;
      mr = mn;
      if (g == 0) stsc[wv * 32 + l31] = sc;
      #pragma unroll
      for (int r = 0; r < 16; ++r) {
        const int rowm = (r & 3) + 8 * (r >> 2) + 4 * g;
        const float sr = stsc[wv * 32 + rowm];
        #pragma unroll
        for (int ct = 0; ct < 8; ++ct) acc[ct][r] *= sr;
      }
    }

    float csum = 0.f;
    short* pw_ = &pB[(wv * 32 + l31) * 40];
    #pragma unroll
    for (int q4 = 0; q4 < 4; ++q4) {
      const float e0 = __expf(sacc[q4*4+0] - mr);
      const float e1 = __expf(sacc[q4*4+1] - mr);
      const float e2 = __expf(sacc[q4*4+2] - mr);
      const float e3 = __expf(sacc[q4*4+3] - mr);
      csum += (e0 + e1) + (e2 + e3);
      bf16x4 pk;
      pk[0]=f2bf(e0); pk[1]=f2bf(e1); pk[2]=f2bf(e2); pk[3]=f2bf(e3);
      *(bf16x4*)&pw_[q4 * 8 + g * 4] = pk;
    }
    csum += __shfl_xor(csum, 32);
    lr += csum;

    const short* pr_ = &pB[(wv * 32 + l31) * 40];
    const bf16x8 pf0 = *(const bf16x8*)&pr_[g * 8];
    const bf16x8 pf1 = *(const bf16x8*)&pr_[16 + g * 8];
    #pragma unroll
    for (int ct = 0; ct < 8; ++ct) {
      const int crow = ct * 32 + l31;
      const short* kNr = &kN[crow * 64];
      const int swc = crow & 7;
      const bf16x8 b0 = *(const bf16x8*)&kNr[((4 * ni + g)     ^ swc) << 3];
      const bf16x8 b1 = *(const bf16x8*)&kNr[((4 * ni + 2 + g) ^ swc) << 3];
      acc[ct] = __builtin_amdgcn_mfma_f32_32x32x16_bf16(pf0, b0, acc[ct], 0, 0, 0);
      acc[ct] = __builtin_amdgcn_mfma_f32_32x32x16_bf16(pf1, b1, acc[ct], 0, 0, 0);
    }
  }

  __syncthreads();
  if (g == 0) { stm[wv * 32 + l31] = mr; stl[wv * 32 + l31] = lr; }
  __syncthreads();
  const int pwv = wv ^ 2;
  const float mo = stm[pwv * 32 + l31];
  const float lo = stl[pwv * 32 + l31];
  const float Mg  = fmaxf(mr, mo);
  const float wsf = __expf(mr - Mg);
  const float Lg  = wsf * lr + __expf(mo - Mg) * lo;
  if (g == 0) { stsc[wv * 32 + l31] = wsf; stLg[wv * 32 + l31] = Lg; }

  float wrow[16], Lrow[16];
  #pragma unroll
  for (int r = 0; r < 16; ++r) {
    const int rowm = (r & 3) + 8 * (r >> 2) + 4 * g;
    wrow[r] = stsc[wv * 32 + rowm];
    Lrow[r] = stLg[wv * 32 + rowm];
  }
  if (ni == 1) {
    #pragma unroll
    for (int r = 0; r < 16; ++r) {
      const int rowm = (r & 3) + 8 * (r >> 2) + 4 * g;
      float* dst = &xch[(mi * 32 + rowm) * 256 + l31];
      #pragma unroll
      for (int ct = 0; ct < 8; ++ct) dst[ct * 32] = acc[ct][r] * wrow[r];
    }
  }
  __syncthreads();
  if (ni == 0) {
    float* ob = outp + ((size_t)b * Mc + m0) * Cc;
    #pragma unroll
    for (int r = 0; r < 16; ++r) {
      const int rowm = (r & 3) + 8 * (r >> 2) + 4 * g;
      const float* sx = &xch[(mi * 32 + rowm) * 256 + l31];
      const float rinv = 1.f / Lrow[r];
      float* orow = ob + (size_t)rowm * Cc + l31;
      #pragma unroll
      for (int ct = 0; ct < 8; ++ct)
        orow[ct * 32] = (acc[ct][r] * wrow[r] + sx[ct * 32]) * rinv;
    }
  }
}

extern "C" void kernel_launch(void* const* d_in, const int* in_sizes, int n_in,
                              void* d_out, int out_size, void* d_ws, size_t ws_size,
                              hipStream_t stream)
{
  const float* fm = (const float*)d_in[0];
  const float* fq = (const float*)d_in[1];
  float* out = (float*)d_out;

  const size_t blob_bytes = (size_t)Bc * NTILES * TILE_BYTES;        // 75,497,472
  const size_t part_bytes = (size_t)NSPLIT * PART_STRIDE * 2;        // 28,311,552 (f16)
  const size_t stat_bytes = (size_t)NSPLIT * STAT_STRIDE * 4;        // 221,184 each
  const size_t need_full  = blob_bytes + part_bytes + 2 * stat_bytes; // ~104.3 MB
  const size_t need_blob1 = blob_bytes;

  if (ws_size >= need_full) {
    char* blob = (char*)d_ws;
    _Float16* part = (_Float16*)(blob + blob_bytes);
    float* mst = (float*)((char*)part + part_bytes);
    float* lst = (float*)((char*)mst + stat_bytes);
    prep_blob<<<Bc * NTILES, 256, 0, stream>>>(fm, blob);
    attn_main3<<<480, 256, 0, stream>>>(blob, fq, nullptr, part, mst, lst, NSPLIT, NSUPER);
    attn_merge6<<<2304, 256, 0, stream>>>(part, mst, lst, out);
  } else if (ws_size >= need_blob1) {
    char* blob = (char*)d_ws;
    prep_blob<<<Bc * NTILES, 256, 0, stream>>>(fm, blob);
    attn_main3<<<80, 256, 0, stream>>>(blob, fq, out, nullptr, nullptr, nullptr, 1, NTILES);
  } else {
    attn_main<<<144, 256, 0, stream>>>(fm, fq, out, nullptr, nullptr, 1, NTILES);
  }
}

// Round 5
// 99.699 us; speedup vs baseline: 2.9438x; 1.0408x over previous
//
#include <hip/hip_runtime.h>
#include <hip/hip_bf16.h>

// Flash-attention formulation of memory_fuse:
//   B=16, C=256, N=4608, M=576
//   S = fm^T fq /16 ; attn = softmax_n ; y[b,m,c] = sum_n fm[c,n] attn[n,m]
// Round 5 = verified round-3 kernel + ONE delta: block-major conflict-free LDS
// layouts (compile-time ds offsets, no XOR swizzle):
//   kT image (32KB): sh(n,c) = (c>>3)*512 + n*8 + (c&7)    [32 cblk][64 n][8]
//   kN image (32KB): sh(n,c) = (n>>3)*2048 + c*8 + (n&7)   [8 nblk][256 c][8]
// Everything else (tiles, vmcnt scheme, reductions, epilogue, merge) is
// byte-identical to the round-3 source that passed.

#define Bc 16
#define Cc 256
#define Nc 4608
#define Mc 576
#define NTILES 72            // 4608/64 n-tiles per batch
#define TILE_BYTES 65536     // [kT 32KB][kN 32KB] per (b,64n-tile)
#define NSPLIT 6
#define NSUPER 12            // 72/6
#define PART_STRIDE 2359296  // 16*576*256 elems per split
#define STAT_STRIDE 9216     // 16*576
#define RESCALE_THR2 7.2f    // ~5 nats in exp2 units

typedef short bf16x8 __attribute__((ext_vector_type(8)));
typedef short bf16x4 __attribute__((ext_vector_type(4)));
typedef float f32x16 __attribute__((ext_vector_type(16)));
typedef unsigned u32x4 __attribute__((ext_vector_type(4)));
typedef _Float16 f16x4 __attribute__((ext_vector_type(4)));

static __device__ __forceinline__ short f2bf(float f) {
  return __builtin_bit_cast(short, __float2bfloat16(f));   // RNE f32->bf16
}
static __device__ __forceinline__ unsigned cvtpk(float lo, float hi) {
  unsigned d;
  asm("v_cvt_pk_bf16_f32 %0, %1, %2" : "=v"(d) : "v"(lo), "v"(hi));
  return d;
}

#define AS1 __attribute__((address_space(1)))
#define AS3 __attribute__((address_space(3)))
static __device__ __forceinline__ void gload16(const char* g, char* l) {
  __builtin_amdgcn_global_load_lds((const AS1 void*)g, (AS3 void*)l, 16, 0, 0);
}

// ---------------------------------------------------------------------------
// Pre-pass: one block per (b, 64n-tile). fm f32 -> bf16 into the block-major
// layouts above, then linear 64KB dump to blob. Item mapping identical to the
// verified round-3 prep; only the two LDS write addresses changed.
__global__ __launch_bounds__(256, 2)
void prep_blob(const float* __restrict__ fm, char* __restrict__ blob)
{
  __shared__ __align__(16) char smem[65536];
  short* kT = (short*)smem;
  short* kN = (short*)(smem + 32768);
  const int tile = blockIdx.x;          // 0..1151
  const int b = tile / NTILES, t = tile % NTILES;
  const int tid = threadIdx.x;
  const float* fmb = fm + (size_t)b * Cc * Nc;
  const int nb = t * 64;

  #pragma unroll 2
  for (int i = 0; i < 8; ++i) {
    const int idx = i * 256 + tid;        // [0,2048)
    const int c   = (idx >> 4) * 2;       // even c; rows c, c+1
    const int n4  = idx & 15;             // n = 4*n4..4*n4+3
    const float* src = fmb + (size_t)c * Nc + nb + n4 * 4;
    const float4 va = *(const float4*)src;
    const float4 vb = *(const float4*)(src + Nc);
    bf16x4 sa, sb;
    sa[0]=f2bf(va.x); sa[1]=f2bf(va.y); sa[2]=f2bf(va.z); sa[3]=f2bf(va.w);
    sb[0]=f2bf(vb.x); sb[1]=f2bf(vb.y); sb[2]=f2bf(vb.z); sb[3]=f2bf(vb.w);
    // kN [nblk][c][8]: n>>3 = n4>>1, n&7 = (n4&1)*4 + k
    short* kNb = &kN[(n4 >> 1) * 2048 + (n4 & 1) * 4];
    *(bf16x4*)&kNb[c * 8]       = sa;
    *(bf16x4*)&kNb[(c + 1) * 8] = sb;
    // kT [cblk][n][8]: pack (c, c+1) pair per n
    short* kTb = &kT[(c >> 3) * 512 + (c & 7)];
    #pragma unroll
    for (int k = 0; k < 4; ++k) {
      const int row = n4 * 4 + k;
      const unsigned pk = (unsigned short)sa[k] | ((unsigned)(unsigned short)sb[k] << 16);
      *(unsigned*)&kTb[row * 8] = pk;
    }
  }
  __syncthreads();
  char* dst = blob + (size_t)tile * TILE_BYTES;
  #pragma unroll
  for (int i = 0; i < 16; ++i) {
    const int off = i * 4096 + tid * 16;
    *(float4*)(dst + off) = *(const float4*)(smem + off);
  }
}

// ---------------------------------------------------------------------------
// Main kernel v5 (= verified round-3 attn_main3 with block-major reads).
__global__ __launch_bounds__(256, 2)
void attn_main5(const char* __restrict__ blob, const float* __restrict__ fq,
                float* __restrict__ outp, _Float16* __restrict__ part,
                float* __restrict__ mstat, float* __restrict__ lstat,
                const int nsplit, const int nsuper)
{
  __shared__ __align__(16) char smem[67072];
  float* stsc= (float*)(smem + 65536);       // [4][32] rescale broadcast
  float* stLg= (float*)(smem + 66048);       // [4][32] L broadcast
  float* stm = (float*)(smem + 66560);       // [4][32] m broadcast

  const int tid  = threadIdx.x;
  const int lane = tid & 63;
  const int l31  = lane & 31;
  const int g    = lane >> 5;
  const int wv   = tid >> 6;

  // XCD-clustered remap: consecutive lids share one (b,s) fm slice.
  const int cpx = gridDim.x >> 3;
  const int bid = blockIdx.x;
  const int lid = (bid & 7) * cpx + (bid >> 3);
  const int mb    = lid % 5;
  const int slice = lid / 5;
  const int b = slice & 15;
  const int s = slice >> 4;

  const int mw = mb * 128 + wv * 32;
  const bool valid = (mw < Mc);
  const int m0 = valid ? mw : (Mc - 64 + (wv & 1) * 32);

  const char* tb0 = blob + (size_t)(b * NTILES + s * nsuper) * TILE_BYTES;
  char* lT = (char*)smem + wv * 8192;
  char* lN = (char*)smem + 32768 + wv * 8192;

  // prologue: issue tile 0 (kT then kN), 8 gloads each per wave
  {
    const char* gt = tb0;
    #pragma unroll
    for (int j = 0; j < 8; ++j) gload16(gt + wv*8192 + j*1024 + lane*16, lT + j*1024);
    #pragma unroll
    for (int j = 0; j < 8; ++j) gload16(gt + 32768 + wv*8192 + j*1024 + lane*16, lN + j*1024);
  }

  // Q fragments, scale = (1/16)*log2(e) folded (softmax in exp2 domain)
  bf16x8 qf[16];
  {
    const float* fqb = fq + (size_t)b * Cc * Mc + m0 + l31;
    #pragma unroll
    for (int kt = 0; kt < 16; ++kt) {
      bf16x8 q;
      #pragma unroll
      for (int j = 0; j < 8; ++j) {
        const int c = kt * 16 + g * 8 + j;
        q[j] = f2bf(fqb[c * Mc] * 0.09016844f);
      }
      qf[kt] = q;
    }
  }

  f32x16 acc[8];
  #pragma unroll
  for (int i = 0; i < 8; ++i)
    #pragma unroll
    for (int e = 0; e < 16; ++e) acc[i][e] = 0.f;
  float m2r = -1e30f, lr = 0.f;     // exp2-domain running max / denom (m = m0+l31)
  u32x4 paw[4];                     // PA fragments (4 k-steps of the 64-n tile)

  for (int it = 0; it < nsuper; ++it) {
    const bool more = (it + 1 < nsuper);
    asm volatile("s_waitcnt vmcnt(8)\ns_barrier" ::: "memory");   // kT ready

    #pragma unroll
    for (int sub = 0; sub < 2; ++sub) {
      // ---- QK^T subtile: S[n(32) x m(32)], A rows n = sub*32+l31 from kT
      f32x16 sacc;
      #pragma unroll
      for (int e = 0; e < 16; ++e) sacc[e] = 0.f;
      // kT [cblk=2kt+g][n][16B]: byte = (2kt+g)*1024 + n*16
      const char* aT = (const char*)smem + g * 1024 + (sub * 32 + l31) * 16;
      __builtin_amdgcn_s_setprio(1);
      #pragma unroll
      for (int kt = 0; kt < 16; ++kt) {
        const bf16x8 a = *(const bf16x8*)(aT + kt * 2048);
        sacc = __builtin_amdgcn_mfma_f32_32x32x16_bf16(a, qf[kt], sacc, 0, 0, 0);
      }
      __builtin_amdgcn_s_setprio(0);

      // ---- online softmax (exp2 domain), lane owns column m = m0+l31
      float pmax = sacc[0];
      #pragma unroll
      for (int r = 1; r < 16; ++r) pmax = fmaxf(pmax, sacc[r]);
      pmax = fmaxf(pmax, __shfl_xor(pmax, 32));

      if (!__all(pmax <= m2r + RESCALE_THR2)) {
        const float mn = fmaxf(m2r, pmax);
        const float sc = exp2f(m2r - mn);
        lr *= sc;
        m2r = mn;
        if (g == 0) stsc[wv * 32 + l31] = sc;
        #pragma unroll
        for (int r = 0; r < 16; ++r) {
          const int rowm = (r & 3) + 8 * (r >> 2) + 4 * g;
          const float sr = stsc[wv * 32 + rowm];
          #pragma unroll
          for (int ct = 0; ct < 8; ++ct) acc[ct][r] *= sr;
        }
      }

      float csum = 0.f;
      #pragma unroll
      for (int r = 0; r < 16; ++r) {
        sacc[r] = exp2f(sacc[r] - m2r);
        csum += sacc[r];
      }
      csum += __shfl_xor(csum, 32);
      lr += csum;

      // ---- P (lane-local, n over regs) -> PA fragments via cvt_pk + permlane32_swap
      #pragma unroll
      for (int ks = 0; ks < 2; ++ks) {
        unsigned w0 = cvtpk(sacc[8*ks+0], sacc[8*ks+1]);
        unsigned w2 = cvtpk(sacc[8*ks+4], sacc[8*ks+5]);
        asm("v_permlane32_swap_b32 %0, %1" : "+v"(w0), "+v"(w2));
        unsigned w1 = cvtpk(sacc[8*ks+2], sacc[8*ks+3]);
        unsigned w3 = cvtpk(sacc[8*ks+6], sacc[8*ks+7]);
        asm("v_permlane32_swap_b32 %0, %1" : "+v"(w1), "+v"(w3));
        u32x4 w; w[0] = w0; w[1] = w1; w[2] = w2; w[3] = w3;
        paw[2*sub + ks] = w;
      }
    }

    // kT consumed by all waves -> refill
    asm volatile("s_waitcnt lgkmcnt(0)\ns_barrier" ::: "memory");
    if (more) {
      const char* gt = tb0 + (size_t)(it + 1) * TILE_BYTES;
      #pragma unroll
      for (int j = 0; j < 8; ++j) gload16(gt + wv*8192 + j*1024 + lane*16, lT + j*1024);
    }

    // kN ready (kT' loads outstanding if issued)
    if (more) asm volatile("s_waitcnt vmcnt(8)\ns_barrier" ::: "memory");
    else      asm volatile("s_waitcnt vmcnt(0)\ns_barrier" ::: "memory");

    // ---- PV: acc[m][c] += P(A, in-register) * fm(B from kN), 4 k-steps
    // kN [nblk=2ks+g][c][16B]: byte = 32768 + (2ks+g)*4096 + c*16
    const char* aN = (const char*)smem + 32768 + g * 4096 + l31 * 16;
    __builtin_amdgcn_s_setprio(1);
    #pragma unroll
    for (int ct = 0; ct < 8; ++ct) {
      #pragma unroll
      for (int ks = 0; ks < 4; ++ks) {
        const bf16x8 bv = *(const bf16x8*)(aN + ks * 8192 + ct * 512);
        acc[ct] = __builtin_amdgcn_mfma_f32_32x32x16_bf16(
            __builtin_bit_cast(bf16x8, paw[ks]), bv, acc[ct], 0, 0, 0);
      }
    }
    __builtin_amdgcn_s_setprio(0);

    // kN consumed -> refill
    asm volatile("s_waitcnt lgkmcnt(0)\ns_barrier" ::: "memory");
    if (more) {
      const char* gt = tb0 + (size_t)(it + 1) * TILE_BYTES;
      #pragma unroll
      for (int j = 0; j < 8; ++j) gload16(gt + 32768 + wv*8192 + j*1024 + lane*16, lN + j*1024);
    }
  }

  // ---- epilogue: broadcast per-m stats to acc rows (wave-private LDS rows)
  if (g == 0) { stLg[wv * 32 + l31] = lr; stm[wv * 32 + l31] = m2r; }

  if (nsplit == 1) {
    if (valid) {
      float* ob = outp + ((size_t)b * Mc + m0) * Cc + l31;
      #pragma unroll
      for (int r = 0; r < 16; ++r) {
        const int rowm = (r & 3) + 8 * (r >> 2) + 4 * g;
        const float rinv = 1.f / stLg[wv * 32 + rowm];
        #pragma unroll
        for (int ct = 0; ct < 8; ++ct)
          ob[(size_t)rowm * Cc + ct * 32] = acc[ct][r] * rinv;
      }
    }
  } else {
    if (valid) {
      _Float16* pb_ = part + (size_t)s * PART_STRIDE + ((size_t)b * Mc + m0) * Cc + l31;
      #pragma unroll
      for (int r = 0; r < 16; ++r) {
        const int rowm = (r & 3) + 8 * (r >> 2) + 4 * g;
        #pragma unroll
        for (int ct = 0; ct < 8; ++ct)
          pb_[(size_t)rowm * Cc + ct * 32] = (_Float16)acc[ct][r];
      }
      if (g == 0) {
        mstat[s * STAT_STRIDE + b * Mc + m0 + l31] = m2r;
        lstat[s * STAT_STRIDE + b * Mc + m0 + l31] = lr;
      }
    }
  }
}

// ---------------------------------------------------------------------------
// Merge the 6 N-split f16 partials (exp2-domain stats). (verbatim round-3)
__global__ __launch_bounds__(256)
void attn_merge6(const _Float16* __restrict__ part, const float* __restrict__ mstat,
                 const float* __restrict__ lstat, float* __restrict__ outp)
{
  const int gid = blockIdx.x * 256 + threadIdx.x;   // 589824 threads
  const int c4 = gid & 63;
  const int bm = gid >> 6;
  float m[NSPLIT];
  float Mg = -1e30f;
  #pragma unroll
  for (int s = 0; s < NSPLIT; ++s) { m[s] = mstat[s * STAT_STRIDE + bm]; Mg = fmaxf(Mg, m[s]); }
  float w[NSPLIT], den = 0.f;
  #pragma unroll
  for (int s = 0; s < NSPLIT; ++s) {
    w[s] = exp2f(m[s] - Mg);
    den += w[s] * lstat[s * STAT_STRIDE + bm];
  }
  const float rinv = 1.f / den;
  const size_t o = (size_t)bm * 256 + c4 * 4;
  float r0 = 0.f, r1 = 0.f, r2 = 0.f, r3 = 0.f;
  #pragma unroll
  for (int s = 0; s < NSPLIT; ++s) {
    const f16x4 a = *(const f16x4*)&part[(size_t)s * PART_STRIDE + o];
    r0 += w[s] * (float)a[0];
    r1 += w[s] * (float)a[1];
    r2 += w[s] * (float)a[2];
    r3 += w[s] * (float)a[3];
  }
  float4 r;
  r.x = r0 * rinv; r.y = r1 * rinv; r.z = r2 * rinv; r.w = r3 * rinv;
  *(float4*)&outp[o] = r;
}

// ---------------------------------------------------------------------------
// Legacy (round-1, verified) single-split kernel — tiny-ws fallback only.
__global__ __launch_bounds__(256, 2)
void attn_main(const float* __restrict__ fm, const float* __restrict__ fq,
               float* __restrict__ outp, const int nsuper)
{
  __shared__ __align__(16) char smem[77824];
  short* kT  = (short*)smem;
  short* kN  = (short*)(smem + 32768);
  short* pB  = (short*)(smem + 65536);
  float* stm = (float*)(smem + 75776);
  float* stl = (float*)(smem + 76288);
  float* stsc= (float*)(smem + 76800);
  float* stLg= (float*)(smem + 77312);
  float* xch = (float*)smem;

  const int tid  = threadIdx.x;
  const int lane = tid & 63;
  const int l31  = lane & 31;
  const int g    = lane >> 5;
  const int wv   = tid >> 6;
  const int mi   = wv & 1;
  const int ni   = wv >> 1;

  const int nblk = gridDim.x;
  const int cpx  = nblk >> 3;
  const int bid  = blockIdx.x;
  const int lid  = (bid & 7) * cpx + (bid >> 3);
  const int qt = lid % 9;
  const int b  = lid / 9;

  const int m0 = qt * 64 + mi * 32;

  bf16x8 qf[16];
  {
    const float* fqb = fq + (size_t)b * Cc * Mc + m0 + l31;
    #pragma unroll
    for (int kt = 0; kt < 16; ++kt) {
      bf16x8 q;
      #pragma unroll
      for (int j = 0; j < 8; ++j) {
        const int c = kt * 16 + g * 8 + j;
        q[j] = f2bf(fqb[c * Mc] * 0.0625f);
      }
      qf[kt] = q;
    }
  }

  f32x16 acc[8];
  #pragma unroll
  for (int i = 0; i < 8; ++i)
    #pragma unroll
    for (int e = 0; e < 16; ++e) acc[i][e] = 0.f;
  float mr = -1e30f, lr = 0.f;

  const float* fmb = fm + (size_t)b * Cc * Nc;
  const int tb = ni * 32;

  for (int it = 0; it < nsuper; ++it) {
    const int nb = it * 64;
    __syncthreads();
    #pragma unroll 2
    for (int i = 0; i < 8; ++i) {
      const int idx = i * 256 + tid;
      const int c   = (idx >> 4) * 2;
      const int n4  = idx & 15;
      const float* src = fmb + (size_t)c * Nc + nb + n4 * 4;
      const float4 va = *(const float4*)src;
      const float4 vb = *(const float4*)(src + Nc);
      bf16x4 sa, sb;
      sa[0]=f2bf(va.x); sa[1]=f2bf(va.y); sa[2]=f2bf(va.z); sa[3]=f2bf(va.w);
      sb[0]=f2bf(vb.x); sb[1]=f2bf(vb.y); sb[2]=f2bf(vb.z); sb[3]=f2bf(vb.w);
      const int bn = n4 >> 1, off = (n4 & 1) * 4;
      *(bf16x4*)&kN[c * 64       + ((bn ^ (c & 7))       << 3) + off] = sa;
      *(bf16x4*)&kN[(c + 1) * 64 + ((bn ^ ((c + 1) & 7)) << 3) + off] = sb;
      const int cb = c >> 3;
      #pragma unroll
      for (int k = 0; k < 4; ++k) {
        const int row = n4 * 4 + k;
        const unsigned pk = (unsigned short)sa[k] | ((unsigned)(unsigned short)sb[k] << 16);
        *(unsigned*)&kT[row * 256 + ((cb ^ (row & 7)) << 3) + (c & 7)] = pk;
      }
    }
    __syncthreads();

    f32x16 sacc;
    #pragma unroll
    for (int e = 0; e < 16; ++e) sacc[e] = 0.f;
    const int nrow = tb + l31;
    const short* kTr = &kT[nrow * 256];
    const int sw = nrow & 7;
    #pragma unroll
    for (int kt = 0; kt < 16; ++kt) {
      const bf16x8 a = *(const bf16x8*)&kTr[((2 * kt + g) ^ sw) << 3];
      sacc = __builtin_amdgcn_mfma_f32_32x32x16_bf16(a, qf[kt], sacc, 0, 0, 0);
    }

    float pmax = sacc[0];
    #pragma unroll
    for (int r = 1; r < 16; ++r) pmax = fmaxf(pmax, sacc[r]);
    pmax = fmaxf(pmax, __shfl_xor(pmax, 32));

    if (!__all(pmax <= mr + 8.f)) {
      const float mn = fmaxf(mr, pmax);
      const float sc = __expf(mr - mn);
      lr *= sc;
      mr = mn;
      if (g == 0) stsc[wv * 32 + l31] = sc;
      #pragma unroll
      for (int r = 0; r < 16; ++r) {
        const int rowm = (r & 3) + 8 * (r >> 2) + 4 * g;
        const float sr = stsc[wv * 32 + rowm];
        #pragma unroll
        for (int ct = 0; ct < 8; ++ct) acc[ct][r] *= sr;
      }
    }

    float csum = 0.f;
    short* pw_ = &pB[(wv * 32 + l31) * 40];
    #pragma unroll
    for (int q4 = 0; q4 < 4; ++q4) {
      const float e0 = __expf(sacc[q4*4+0] - mr);
      const float e1 = __expf(sacc[q4*4+1] - mr);
      const float e2 = __expf(sacc[q4*4+2] - mr);
      const float e3 = __expf(sacc[q4*4+3] - mr);
      csum += (e0 + e1) + (e2 + e3);
      bf16x4 pk;
      pk[0]=f2bf(e0); pk[1]=f2bf(e1); pk[2]=f2bf(e2); pk[3]=f2bf(e3);
      *(bf16x4*)&pw_[q4 * 8 + g * 4] = pk;
    }
    csum += __shfl_xor(csum, 32);
    lr += csum;

    const short* pr_ = &pB[(wv * 32 + l31) * 40];
    const bf16x8 pf0 = *(const bf16x8*)&pr_[g * 8];
    const bf16x8 pf1 = *(const bf16x8*)&pr_[16 + g * 8];
    #pragma unroll
    for (int ct = 0; ct < 8; ++ct) {
      const int crow = ct * 32 + l31;
      const short* kNr = &kN[crow * 64];
      const int swc = crow & 7;
      const bf16x8 b0 = *(const bf16x8*)&kNr[((4 * ni + g)     ^ swc) << 3];
      const bf16x8 b1 = *(const bf16x8*)&kNr[((4 * ni + 2 + g) ^ swc) << 3];
      acc[ct] = __builtin_amdgcn_mfma_f32_32x32x16_bf16(pf0, b0, acc[ct], 0, 0, 0);
      acc[ct] = __builtin_amdgcn_mfma_f32_32x32x16_bf16(pf1, b1, acc[ct], 0, 0, 0);
    }
  }

  __syncthreads();
  if (g == 0) { stm[wv * 32 + l31] = mr; stl[wv * 32 + l31] = lr; }
  __syncthreads();
  const int pwv = wv ^ 2;
  const float mo = stm[pwv * 32 + l31];
  const float lo = stl[pwv * 32 + l31];
  const float Mg  = fmaxf(mr, mo);
  const float wsf = __expf(mr - Mg);
  const float Lg  = wsf * lr + __expf(mo - Mg) * lo;
  if (g == 0) { stsc[wv * 32 + l31] = wsf; stLg[wv * 32 + l31] = Lg; }

  float wrow[16], Lrow[16];
  #pragma unroll
  for (int r = 0; r < 16; ++r) {
    const int rowm = (r & 3) + 8 * (r >> 2) + 4 * g;
    wrow[r] = stsc[wv * 32 + rowm];
    Lrow[r] = stLg[wv * 32 + rowm];
  }
  if (ni == 1) {
    #pragma unroll
    for (int r = 0; r < 16; ++r) {
      const int rowm = (r & 3) + 8 * (r >> 2) + 4 * g;
      float* dst = &xch[(mi * 32 + rowm) * 256 + l31];
      #pragma unroll
      for (int ct = 0; ct < 8; ++ct) dst[ct * 32] = acc[ct][r] * wrow[r];
    }
  }
  __syncthreads();
  if (ni == 0) {
    float* ob = outp + ((size_t)b * Mc + m0) * Cc;
    #pragma unroll
    for (int r = 0; r < 16; ++r) {
      const int rowm = (r & 3) + 8 * (r >> 2) + 4 * g;
      const float* sx = &xch[(mi * 32 + rowm) * 256 + l31];
      const float rinv = 1.f / Lrow[r];
      float* orow = ob + (size_t)rowm * Cc + l31;
      #pragma unroll
      for (int ct = 0; ct < 8; ++ct)
        orow[ct * 32] = (acc[ct][r] * wrow[r] + sx[ct * 32]) * rinv;
    }
  }
}

extern "C" void kernel_launch(void* const* d_in, const int* in_sizes, int n_in,
                              void* d_out, int out_size, void* d_ws, size_t ws_size,
                              hipStream_t stream)
{
  const float* fm = (const float*)d_in[0];
  const float* fq = (const float*)d_in[1];
  float* out = (float*)d_out;

  const size_t blob_bytes = (size_t)Bc * NTILES * TILE_BYTES;        // 75,497,472
  const size_t part_bytes = (size_t)NSPLIT * PART_STRIDE * 2;        // 28,311,552 (f16)
  const size_t stat_bytes = (size_t)NSPLIT * STAT_STRIDE * 4;        // 221,184 each
  const size_t need_full  = blob_bytes + part_bytes + 2 * stat_bytes; // ~104.3 MB
  const size_t need_blob1 = blob_bytes;

  if (ws_size >= need_full) {
    char* blob = (char*)d_ws;
    _Float16* part = (_Float16*)(blob + blob_bytes);
    float* mst = (float*)((char*)part + part_bytes);
    float* lst = (float*)((char*)mst + stat_bytes);
    prep_blob<<<Bc * NTILES, 256, 0, stream>>>(fm, blob);
    attn_main5<<<480, 256, 0, stream>>>(blob, fq, nullptr, part, mst, lst, NSPLIT, NSUPER);
    attn_merge6<<<2304, 256, 0, stream>>>(part, mst, lst, out);
  } else if (ws_size >= need_blob1) {
    char* blob = (char*)d_ws;
    prep_blob<<<Bc * NTILES, 256, 0, stream>>>(fm, blob);
    attn_main5<<<80, 256, 0, stream>>>(blob, fq, out, nullptr, nullptr, nullptr, 1, NTILES);
  } else {
    attn_main<<<144, 256, 0, stream>>>(fm, fq, out, NTILES);
  }
}

// Round 6
// 96.215 us; speedup vs baseline: 3.0505x; 1.0362x over previous
//
#include <hip/hip_runtime.h>
#include <hip/hip_bf16.h>

// Flash-attention formulation of memory_fuse:
//   B=16, C=256, N=4608, M=576
//   S = fm^T fq /16 ; attn = softmax_n ; y[b,m,c] = sum_n fm[c,n] attn[n,m]
// Round 6 = verified round-5 base + softmax VALU diet (raw v_exp_f32, max3
// tree, partial csums) + earlier kT' prefetch issue + setprio removed.
// Layouts, vmcnt counts, MFMA mappings, epilogue, merge: verbatim round 5.

#define Bc 16
#define Cc 256
#define Nc 4608
#define Mc 576
#define NTILES 72            // 4608/64 n-tiles per batch
#define TILE_BYTES 65536     // [kT 32KB][kN 32KB] per (b,64n-tile)
#define NSPLIT 6
#define NSUPER 12            // 72/6
#define PART_STRIDE 2359296  // 16*576*256 elems per split
#define STAT_STRIDE 9216     // 16*576
#define RESCALE_THR2 7.2f    // ~5 nats in exp2 units

typedef short bf16x8 __attribute__((ext_vector_type(8)));
typedef short bf16x4 __attribute__((ext_vector_type(4)));
typedef float f32x16 __attribute__((ext_vector_type(16)));
typedef unsigned u32x4 __attribute__((ext_vector_type(4)));
typedef _Float16 f16x4 __attribute__((ext_vector_type(4)));

static __device__ __forceinline__ short f2bf(float f) {
  return __builtin_bit_cast(short, __float2bfloat16(f));   // RNE f32->bf16
}
static __device__ __forceinline__ unsigned cvtpk(float lo, float hi) {
  unsigned d;
  asm("v_cvt_pk_bf16_f32 %0, %1, %2" : "=v"(d) : "v"(lo), "v"(hi));
  return d;
}
static __device__ __forceinline__ float expraw(float x) {   // 2^x, single instr
  float d;
  asm("v_exp_f32 %0, %1" : "=v"(d) : "v"(x));
  return d;
}
static __device__ __forceinline__ float max3f(float a, float b, float c) {
  float d;
  asm("v_max3_f32 %0, %1, %2, %3" : "=v"(d) : "v"(a), "v"(b), "v"(c));
  return d;
}

#define AS1 __attribute__((address_space(1)))
#define AS3 __attribute__((address_space(3)))
static __device__ __forceinline__ void gload16(const char* g, char* l) {
  __builtin_amdgcn_global_load_lds((const AS1 void*)g, (AS3 void*)l, 16, 0, 0);
}

// ---------------------------------------------------------------------------
// Pre-pass (verbatim round-5, verified): fm f32 -> bf16 block-major layouts:
//   kT image (32KB): sh(n,c) = (c>>3)*512 + n*8 + (c&7)    [32 cblk][64 n][8]
//   kN image (32KB): sh(n,c) = (n>>3)*2048 + c*8 + (n&7)   [8 nblk][256 c][8]
__global__ __launch_bounds__(256, 2)
void prep_blob(const float* __restrict__ fm, char* __restrict__ blob)
{
  __shared__ __align__(16) char smem[65536];
  short* kT = (short*)smem;
  short* kN = (short*)(smem + 32768);
  const int tile = blockIdx.x;          // 0..1151
  const int b = tile / NTILES, t = tile % NTILES;
  const int tid = threadIdx.x;
  const float* fmb = fm + (size_t)b * Cc * Nc;
  const int nb = t * 64;

  #pragma unroll 2
  for (int i = 0; i < 8; ++i) {
    const int idx = i * 256 + tid;        // [0,2048)
    const int c   = (idx >> 4) * 2;       // even c; rows c, c+1
    const int n4  = idx & 15;             // n = 4*n4..4*n4+3
    const float* src = fmb + (size_t)c * Nc + nb + n4 * 4;
    const float4 va = *(const float4*)src;
    const float4 vb = *(const float4*)(src + Nc);
    bf16x4 sa, sb;
    sa[0]=f2bf(va.x); sa[1]=f2bf(va.y); sa[2]=f2bf(va.z); sa[3]=f2bf(va.w);
    sb[0]=f2bf(vb.x); sb[1]=f2bf(vb.y); sb[2]=f2bf(vb.z); sb[3]=f2bf(vb.w);
    short* kNb = &kN[(n4 >> 1) * 2048 + (n4 & 1) * 4];
    *(bf16x4*)&kNb[c * 8]       = sa;
    *(bf16x4*)&kNb[(c + 1) * 8] = sb;
    short* kTb = &kT[(c >> 3) * 512 + (c & 7)];
    #pragma unroll
    for (int k = 0; k < 4; ++k) {
      const int row = n4 * 4 + k;
      const unsigned pk = (unsigned short)sa[k] | ((unsigned)(unsigned short)sb[k] << 16);
      *(unsigned*)&kTb[row * 8] = pk;
    }
  }
  __syncthreads();
  char* dst = blob + (size_t)tile * TILE_BYTES;
  #pragma unroll
  for (int i = 0; i < 16; ++i) {
    const int off = i * 4096 + tid * 16;
    *(float4*)(dst + off) = *(const float4*)(smem + off);
  }
}

// ---------------------------------------------------------------------------
// Main kernel v6.
__global__ __launch_bounds__(256, 2)
void attn_main6(const char* __restrict__ blob, const float* __restrict__ fq,
                float* __restrict__ outp, _Float16* __restrict__ part,
                float* __restrict__ mstat, float* __restrict__ lstat,
                const int nsplit, const int nsuper)
{
  __shared__ __align__(16) char smem[67072];
  float* stsc= (float*)(smem + 65536);       // [4][32] rescale broadcast
  float* stLg= (float*)(smem + 66048);       // [4][32] L broadcast
  float* stm = (float*)(smem + 66560);       // [4][32] m broadcast

  const int tid  = threadIdx.x;
  const int lane = tid & 63;
  const int l31  = lane & 31;
  const int g    = lane >> 5;
  const int wv   = tid >> 6;

  // XCD-clustered remap: consecutive lids share one (b,s) fm slice.
  const int cpx = gridDim.x >> 3;
  const int bid = blockIdx.x;
  const int lid = (bid & 7) * cpx + (bid >> 3);
  const int mb    = lid % 5;
  const int slice = lid / 5;
  const int b = slice & 15;
  const int s = slice >> 4;

  const int mw = mb * 128 + wv * 32;
  const bool valid = (mw < Mc);
  const int m0 = valid ? mw : (Mc - 64 + (wv & 1) * 32);

  const char* tb0 = blob + (size_t)(b * NTILES + s * nsuper) * TILE_BYTES;
  char* lT = (char*)smem + wv * 8192;
  char* lN = (char*)smem + 32768 + wv * 8192;

  // prologue: issue tile 0 (kT then kN), 8 gloads each per wave
  {
    const char* gt = tb0;
    #pragma unroll
    for (int j = 0; j < 8; ++j) gload16(gt + wv*8192 + j*1024 + lane*16, lT + j*1024);
    #pragma unroll
    for (int j = 0; j < 8; ++j) gload16(gt + 32768 + wv*8192 + j*1024 + lane*16, lN + j*1024);
  }

  // Q fragments, scale = (1/16)*log2(e) folded (softmax in exp2 domain)
  bf16x8 qf[16];
  {
    const float* fqb = fq + (size_t)b * Cc * Mc + m0 + l31;
    #pragma unroll
    for (int kt = 0; kt < 16; ++kt) {
      bf16x8 q;
      #pragma unroll
      for (int j = 0; j < 8; ++j) {
        const int c = kt * 16 + g * 8 + j;
        q[j] = f2bf(fqb[c * Mc] * 0.09016844f);
      }
      qf[kt] = q;
    }
  }

  f32x16 acc[8];
  #pragma unroll
  for (int i = 0; i < 8; ++i)
    #pragma unroll
    for (int e = 0; e < 16; ++e) acc[i][e] = 0.f;
  float m2r = -1e30f, lr = 0.f;     // exp2-domain running max / denom (m = m0+l31)
  u32x4 paw[4];                     // PA fragments (4 k-steps of the 64-n tile)

  for (int it = 0; it < nsuper; ++it) {
    const bool more = (it + 1 < nsuper);
    asm volatile("s_waitcnt vmcnt(8)\ns_barrier" ::: "memory");   // kT ready

    // ================= QK^T sub0 + softmax sub0 =================
    {
      f32x16 sacc;
      #pragma unroll
      for (int e = 0; e < 16; ++e) sacc[e] = 0.f;
      const char* aT = (const char*)smem + g * 1024 + l31 * 16;   // rows 0..31
      #pragma unroll
      for (int kt = 0; kt < 16; ++kt) {
        const bf16x8 a = *(const bf16x8*)(aT + kt * 2048);
        sacc = __builtin_amdgcn_mfma_f32_32x32x16_bf16(a, qf[kt], sacc, 0, 0, 0);
      }
      // pmax via max3 tree
      float t0 = max3f(sacc[0], sacc[1], sacc[2]);
      float t1 = max3f(sacc[3], sacc[4], sacc[5]);
      float t2 = max3f(sacc[6], sacc[7], sacc[8]);
      float t3 = max3f(sacc[9], sacc[10], sacc[11]);
      float t4 = max3f(sacc[12], sacc[13], sacc[14]);
      float pmax = fmaxf(max3f(max3f(t0, t1, t2), t3, t4), sacc[15]);
      pmax = fmaxf(pmax, __shfl_xor(pmax, 32));

      if (!__all(pmax <= m2r + RESCALE_THR2)) {
        const float mn = fmaxf(m2r, pmax);
        const float sc = expraw(m2r - mn);
        lr *= sc;
        m2r = mn;
        if (g == 0) stsc[wv * 32 + l31] = sc;
        #pragma unroll
        for (int r = 0; r < 16; ++r) {
          const int rowm = (r & 3) + 8 * (r >> 2) + 4 * g;
          const float sr = stsc[wv * 32 + rowm];
          #pragma unroll
          for (int ct = 0; ct < 8; ++ct) acc[ct][r] *= sr;
        }
      }

      float cs0 = 0.f, cs1 = 0.f, cs2 = 0.f, cs3 = 0.f;
      #pragma unroll
      for (int r = 0; r < 16; r += 4) {
        sacc[r+0] = expraw(sacc[r+0] - m2r); cs0 += sacc[r+0];
        sacc[r+1] = expraw(sacc[r+1] - m2r); cs1 += sacc[r+1];
        sacc[r+2] = expraw(sacc[r+2] - m2r); cs2 += sacc[r+2];
        sacc[r+3] = expraw(sacc[r+3] - m2r); cs3 += sacc[r+3];
      }
      float csum = (cs0 + cs1) + (cs2 + cs3);
      csum += __shfl_xor(csum, 32);
      lr += csum;

      #pragma unroll
      for (int ks = 0; ks < 2; ++ks) {
        unsigned w0 = cvtpk(sacc[8*ks+0], sacc[8*ks+1]);
        unsigned w2 = cvtpk(sacc[8*ks+4], sacc[8*ks+5]);
        asm("v_permlane32_swap_b32 %0, %1" : "+v"(w0), "+v"(w2));
        unsigned w1 = cvtpk(sacc[8*ks+2], sacc[8*ks+3]);
        unsigned w3 = cvtpk(sacc[8*ks+6], sacc[8*ks+7]);
        asm("v_permlane32_swap_b32 %0, %1" : "+v"(w1), "+v"(w3));
        u32x4 w; w[0] = w0; w[1] = w1; w[2] = w2; w[3] = w3;
        paw[ks] = w;
      }
    }

    // ================= QK^T sub1 (compute only) =================
    f32x16 sacc1;
    {
      #pragma unroll
      for (int e = 0; e < 16; ++e) sacc1[e] = 0.f;
      const char* aT = (const char*)smem + g * 1024 + (32 + l31) * 16; // rows 32..63
      #pragma unroll
      for (int kt = 0; kt < 16; ++kt) {
        const bf16x8 a = *(const bf16x8*)(aT + kt * 2048);
        sacc1 = __builtin_amdgcn_mfma_f32_32x32x16_bf16(a, qf[kt], sacc1, 0, 0, 0);
      }
    }

    // kT fully consumed by all waves -> refill early (covered by SM1 below)
    asm volatile("s_waitcnt lgkmcnt(0)\ns_barrier" ::: "memory");
    if (more) {
      const char* gt = tb0 + (size_t)(it + 1) * TILE_BYTES;
      #pragma unroll
      for (int j = 0; j < 8; ++j) gload16(gt + wv*8192 + j*1024 + lane*16, lT + j*1024);
    }

    // ================= softmax sub1 =================
    {
      float t0 = max3f(sacc1[0], sacc1[1], sacc1[2]);
      float t1 = max3f(sacc1[3], sacc1[4], sacc1[5]);
      float t2 = max3f(sacc1[6], sacc1[7], sacc1[8]);
      float t3 = max3f(sacc1[9], sacc1[10], sacc1[11]);
      float t4 = max3f(sacc1[12], sacc1[13], sacc1[14]);
      float pmax = fmaxf(max3f(max3f(t0, t1, t2), t3, t4), sacc1[15]);
      pmax = fmaxf(pmax, __shfl_xor(pmax, 32));

      if (!__all(pmax <= m2r + RESCALE_THR2)) {
        const float mn = fmaxf(m2r, pmax);
        const float sc = expraw(m2r - mn);
        lr *= sc;
        m2r = mn;
        if (g == 0) stsc[wv * 32 + l31] = sc;
        #pragma unroll
        for (int r = 0; r < 16; ++r) {
          const int rowm = (r & 3) + 8 * (r >> 2) + 4 * g;
          const float sr = stsc[wv * 32 + rowm];
          #pragma unroll
          for (int ct = 0; ct < 8; ++ct) acc[ct][r] *= sr;
        }
      }

      float cs0 = 0.f, cs1 = 0.f, cs2 = 0.f, cs3 = 0.f;
      #pragma unroll
      for (int r = 0; r < 16; r += 4) {
        sacc1[r+0] = expraw(sacc1[r+0] - m2r); cs0 += sacc1[r+0];
        sacc1[r+1] = expraw(sacc1[r+1] - m2r); cs1 += sacc1[r+1];
        sacc1[r+2] = expraw(sacc1[r+2] - m2r); cs2 += sacc1[r+2];
        sacc1[r+3] = expraw(sacc1[r+3] - m2r); cs3 += sacc1[r+3];
      }
      float csum = (cs0 + cs1) + (cs2 + cs3);
      csum += __shfl_xor(csum, 32);
      lr += csum;

      #pragma unroll
      for (int ks = 0; ks < 2; ++ks) {
        unsigned w0 = cvtpk(sacc1[8*ks+0], sacc1[8*ks+1]);
        unsigned w2 = cvtpk(sacc1[8*ks+4], sacc1[8*ks+5]);
        asm("v_permlane32_swap_b32 %0, %1" : "+v"(w0), "+v"(w2));
        unsigned w1 = cvtpk(sacc1[8*ks+2], sacc1[8*ks+3]);
        unsigned w3 = cvtpk(sacc1[8*ks+6], sacc1[8*ks+7]);
        asm("v_permlane32_swap_b32 %0, %1" : "+v"(w1), "+v"(w3));
        u32x4 w; w[0] = w0; w[1] = w1; w[2] = w2; w[3] = w3;
        paw[2 + ks] = w;
      }
    }

    // kN ready (kT' loads outstanding if issued)
    if (more) asm volatile("s_waitcnt vmcnt(8)\ns_barrier" ::: "memory");
    else      asm volatile("s_waitcnt vmcnt(0)\ns_barrier" ::: "memory");

    // ---- PV: acc[m][c] += P(A, in-register) * fm(B from kN), 4 k-steps
    const char* aN = (const char*)smem + 32768 + g * 4096 + l31 * 16;
    #pragma unroll
    for (int ct = 0; ct < 8; ++ct) {
      #pragma unroll
      for (int ks = 0; ks < 4; ++ks) {
        const bf16x8 bv = *(const bf16x8*)(aN + ks * 8192 + ct * 512);
        acc[ct] = __builtin_amdgcn_mfma_f32_32x32x16_bf16(
            __builtin_bit_cast(bf16x8, paw[ks]), bv, acc[ct], 0, 0, 0);
      }
    }

    // kN consumed -> refill
    asm volatile("s_waitcnt lgkmcnt(0)\ns_barrier" ::: "memory");
    if (more) {
      const char* gt = tb0 + (size_t)(it + 1) * TILE_BYTES;
      #pragma unroll
      for (int j = 0; j < 8; ++j) gload16(gt + 32768 + wv*8192 + j*1024 + lane*16, lN + j*1024);
    }
  }

  // ---- epilogue: broadcast per-m stats to acc rows (wave-private LDS rows)
  if (g == 0) { stLg[wv * 32 + l31] = lr; stm[wv * 32 + l31] = m2r; }

  if (nsplit == 1) {
    if (valid) {
      float* ob = outp + ((size_t)b * Mc + m0) * Cc + l31;
      #pragma unroll
      for (int r = 0; r < 16; ++r) {
        const int rowm = (r & 3) + 8 * (r >> 2) + 4 * g;
        const float rinv = 1.f / stLg[wv * 32 + rowm];
        #pragma unroll
        for (int ct = 0; ct < 8; ++ct)
          ob[(size_t)rowm * Cc + ct * 32] = acc[ct][r] * rinv;
      }
    }
  } else {
    if (valid) {
      _Float16* pb_ = part + (size_t)s * PART_STRIDE + ((size_t)b * Mc + m0) * Cc + l31;
      #pragma unroll
      for (int r = 0; r < 16; ++r) {
        const int rowm = (r & 3) + 8 * (r >> 2) + 4 * g;
        #pragma unroll
        for (int ct = 0; ct < 8; ++ct)
          pb_[(size_t)rowm * Cc + ct * 32] = (_Float16)acc[ct][r];
      }
      if (g == 0) {
        mstat[s * STAT_STRIDE + b * Mc + m0 + l31] = m2r;
        lstat[s * STAT_STRIDE + b * Mc + m0 + l31] = lr;
      }
    }
  }
}

// ---------------------------------------------------------------------------
// Merge the 6 N-split f16 partials (exp2-domain stats). (verbatim round-5)
__global__ __launch_bounds__(256)
void attn_merge6(const _Float16* __restrict__ part, const float* __restrict__ mstat,
                 const float* __restrict__ lstat, float* __restrict__ outp)
{
  const int gid = blockIdx.x * 256 + threadIdx.x;   // 589824 threads
  const int c4 = gid & 63;
  const int bm = gid >> 6;
  float m[NSPLIT];
  float Mg = -1e30f;
  #pragma unroll
  for (int s = 0; s < NSPLIT; ++s) { m[s] = mstat[s * STAT_STRIDE + bm]; Mg = fmaxf(Mg, m[s]); }
  float w[NSPLIT], den = 0.f;
  #pragma unroll
  for (int s = 0; s < NSPLIT; ++s) {
    w[s] = exp2f(m[s] - Mg);
    den += w[s] * lstat[s * STAT_STRIDE + bm];
  }
  const float rinv = 1.f / den;
  const size_t o = (size_t)bm * 256 + c4 * 4;
  float r0 = 0.f, r1 = 0.f, r2 = 0.f, r3 = 0.f;
  #pragma unroll
  for (int s = 0; s < NSPLIT; ++s) {
    const f16x4 a = *(const f16x4*)&part[(size_t)s * PART_STRIDE + o];
    r0 += w[s] * (float)a[0];
    r1 += w[s] * (float)a[1];
    r2 += w[s] * (float)a[2];
    r3 += w[s] * (float)a[3];
  }
  float4 r;
  r.x = r0 * rinv; r.y = r1 * rinv; r.z = r2 * rinv; r.w = r3 * rinv;
  *(float4*)&outp[o] = r;
}

// ---------------------------------------------------------------------------
// Legacy (round-1, verified) single-split kernel — tiny-ws fallback only.
__global__ __launch_bounds__(256, 2)
void attn_main(const float* __restrict__ fm, const float* __restrict__ fq,
               float* __restrict__ outp, const int nsuper)
{
  __shared__ __align__(16) char smem[77824];
  short* kT  = (short*)smem;
  short* kN  = (short*)(smem + 32768);
  short* pB  = (short*)(smem + 65536);
  float* stm = (float*)(smem + 75776);
  float* stl = (float*)(smem + 76288);
  float* stsc= (float*)(smem + 76800);
  float* stLg= (float*)(smem + 77312);
  float* xch = (float*)smem;

  const int tid  = threadIdx.x;
  const int lane = tid & 63;
  const int l31  = lane & 31;
  const int g    = lane >> 5;
  const int wv   = tid >> 6;
  const int mi   = wv & 1;
  const int ni   = wv >> 1;

  const int nblk = gridDim.x;
  const int cpx  = nblk >> 3;
  const int bid  = blockIdx.x;
  const int lid  = (bid & 7) * cpx + (bid >> 3);
  const int qt = lid % 9;
  const int b  = lid / 9;

  const int m0 = qt * 64 + mi * 32;

  bf16x8 qf[16];
  {
    const float* fqb = fq + (size_t)b * Cc * Mc + m0 + l31;
    #pragma unroll
    for (int kt = 0; kt < 16; ++kt) {
      bf16x8 q;
      #pragma unroll
      for (int j = 0; j < 8; ++j) {
        const int c = kt * 16 + g * 8 + j;
        q[j] = f2bf(fqb[c * Mc] * 0.0625f);
      }
      qf[kt] = q;
    }
  }

  f32x16 acc[8];
  #pragma unroll
  for (int i = 0; i < 8; ++i)
    #pragma unroll
    for (int e = 0; e < 16; ++e) acc[i][e] = 0.f;
  float mr = -1e30f, lr = 0.f;

  const float* fmb = fm + (size_t)b * Cc * Nc;
  const int tb = ni * 32;

  for (int it = 0; it < nsuper; ++it) {
    const int nb = it * 64;
    __syncthreads();
    #pragma unroll 2
    for (int i = 0; i < 8; ++i) {
      const int idx = i * 256 + tid;
      const int c   = (idx >> 4) * 2;
      const int n4  = idx & 15;
      const float* src = fmb + (size_t)c * Nc + nb + n4 * 4;
      const float4 va = *(const float4*)src;
      const float4 vb = *(const float4*)(src + Nc);
      bf16x4 sa, sb;
      sa[0]=f2bf(va.x); sa[1]=f2bf(va.y); sa[2]=f2bf(va.z); sa[3]=f2bf(va.w);
      sb[0]=f2bf(vb.x); sb[1]=f2bf(vb.y); sb[2]=f2bf(vb.z); sb[3]=f2bf(vb.w);
      const int bn = n4 >> 1, off = (n4 & 1) * 4;
      *(bf16x4*)&kN[c * 64       + ((bn ^ (c & 7))       << 3) + off] = sa;
      *(bf16x4*)&kN[(c + 1) * 64 + ((bn ^ ((c + 1) & 7)) << 3) + off] = sb;
      const int cb = c >> 3;
      #pragma unroll
      for (int k = 0; k < 4; ++k) {
        const int row = n4 * 4 + k;
        const unsigned pk = (unsigned short)sa[k] | ((unsigned)(unsigned short)sb[k] << 16);
        *(unsigned*)&kT[row * 256 + ((cb ^ (row & 7)) << 3) + (c & 7)] = pk;
      }
    }
    __syncthreads();

    f32x16 sacc;
    #pragma unroll
    for (int e = 0; e < 16; ++e) sacc[e] = 0.f;
    const int nrow = tb + l31;
    const short* kTr = &kT[nrow * 256];
    const int sw = nrow & 7;
    #pragma unroll
    for (int kt = 0; kt < 16; ++kt) {
      const bf16x8 a = *(const bf16x8*)&kTr[((2 * kt + g) ^ sw) << 3];
      sacc = __builtin_amdgcn_mfma_f32_32x32x16_bf16(a, qf[kt], sacc, 0, 0, 0);
    }

    float pmax = sacc[0];
    #pragma unroll
    for (int r = 1; r < 16; ++r) pmax = fmaxf(pmax, sacc[r]);
    pmax = fmaxf(pmax, __shfl_xor(pmax, 32));

    if (!__all(pmax <= mr + 8.f)) {
      const float mn = fmaxf(mr, pmax);
      const float sc = __expf(mr - mn);
      lr *= sc;
      mr = mn;
      if (g == 0) stsc[wv * 32 + l31] = sc;
      #pragma unroll
      for (int r = 0; r < 16; ++r) {
        const int rowm = (r & 3) + 8 * (r >> 2) + 4 * g;
        const float sr = stsc[wv * 32 + rowm];
        #pragma unroll
        for (int ct = 0; ct < 8; ++ct) acc[ct][r] *= sr;
      }
    }

    float csum = 0.f;
    short* pw_ = &pB[(wv * 32 + l31) * 40];
    #pragma unroll
    for (int q4 = 0; q4 < 4; ++q4) {
      const float e0 = __expf(sacc[q4*4+0] - mr);
      const float e1 = __expf(sacc[q4*4+1] - mr);
      const float e2 = __expf(sacc[q4*4+2] - mr);
      const float e3 = __expf(sacc[q4*4+3] - mr);
      csum += (e0 + e1) + (e2 + e3);
      bf16x4 pk;
      pk[0]=f2bf(e0); pk[1]=f2bf(e1); pk[2]=f2bf(e2); pk[3]=f2bf(e3);
      *(bf16x4*)&pw_[q4 * 8 + g * 4] = pk;
    }
    csum += __shfl_xor(csum, 32);
    lr += csum;

    const short* pr_ = &pB[(wv * 32 + l31) * 40];
    const bf16x8 pf0 = *(const bf16x8*)&pr_[g * 8];
    const bf16x8 pf1 = *(const bf16x8*)&pr_[16 + g * 8];
    #pragma unroll
    for (int ct = 0; ct < 8; ++ct) {
      const int crow = ct * 32 + l31;
      const short* kNr = &kN[crow * 64];
      const int swc = crow & 7;
      const bf16x8 b0 = *(const bf16x8*)&kNr[((4 * ni + g)     ^ swc) << 3];
      const bf16x8 b1 = *(const bf16x8*)&kNr[((4 * ni + 2 + g) ^ swc) << 3];
      acc[ct] = __builtin_amdgcn_mfma_f32_32x32x16_bf16(pf0, b0, acc[ct], 0, 0, 0);
      acc[ct] = __builtin_amdgcn_mfma_f32_32x32x16_bf16(pf1, b1, acc[ct], 0, 0, 0);
    }
  }

  __syncthreads();
  if (g == 0) { stm[wv * 32 + l31] = mr; stl[wv * 32 + l31] = lr; }
  __syncthreads();
  const int pwv = wv ^ 2;
  const float mo = stm[pwv * 32 + l31];
  const float lo = stl[pwv * 32 + l31];
  const float Mg  = fmaxf(mr, mo);
  const float wsf = __expf(mr - Mg);
  const float Lg  = wsf * lr + __expf(mo - Mg) * lo;
  if (g == 0) { stsc[wv * 32 + l31] = wsf; stLg[wv * 32 + l31] = Lg; }

  float wrow[16], Lrow[16];
  #pragma unroll
  for (int r = 0; r < 16; ++r) {
    const int rowm = (r & 3) + 8 * (r >> 2) + 4 * g;
    wrow[r] = stsc[wv * 32 + rowm];
    Lrow[r] = stLg[wv * 32 + rowm];
  }
  if (ni == 1) {
    #pragma unroll
    for (int r = 0; r < 16; ++r) {
      const int rowm = (r & 3) + 8 * (r >> 2) + 4 * g;
      float* dst = &xch[(mi * 32 + rowm) * 256 + l31];
      #pragma unroll
      for (int ct = 0; ct < 8; ++ct) dst[ct * 32] = acc[ct][r] * wrow[r];
    }
  }
  __syncthreads();
  if (ni == 0) {
    float* ob = outp + ((size_t)b * Mc + m0) * Cc;
    #pragma unroll
    for (int r = 0; r < 16; ++r) {
      const int rowm = (r & 3) + 8 * (r >> 2) + 4 * g;
      const float* sx = &xch[(mi * 32 + rowm) * 256 + l31];
      const float rinv = 1.f / Lrow[r];
      float* orow = ob + (size_t)rowm * Cc + l31;
      #pragma unroll
      for (int ct = 0; ct < 8; ++ct)
        orow[ct * 32] = (acc[ct][r] * wrow[r] + sx[ct * 32]) * rinv;
    }
  }
}

extern "C" void kernel_launch(void* const* d_in, const int* in_sizes, int n_in,
                              void* d_out, int out_size, void* d_ws, size_t ws_size,
                              hipStream_t stream)
{
  const float* fm = (const float*)d_in[0];
  const float* fq = (const float*)d_in[1];
  float* out = (float*)d_out;

  const size_t blob_bytes = (size_t)Bc * NTILES * TILE_BYTES;        // 75,497,472
  const size_t part_bytes = (size_t)NSPLIT * PART_STRIDE * 2;        // 28,311,552 (f16)
  const size_t stat_bytes = (size_t)NSPLIT * STAT_STRIDE * 4;        // 221,184 each
  const size_t need_full  = blob_bytes + part_bytes + 2 * stat_bytes; // ~104.3 MB
  const size_t need_blob1 = blob_bytes;

  if (ws_size >= need_full) {
    char* blob = (char*)d_ws;
    _Float16* part = (_Float16*)(blob + blob_bytes);
    float* mst = (float*)((char*)part + part_bytes);
    float* lst = (float*)((char*)mst + stat_bytes);
    prep_blob<<<Bc * NTILES, 256, 0, stream>>>(fm, blob);
    attn_main6<<<480, 256, 0, stream>>>(blob, fq, nullptr, part, mst, lst, NSPLIT, NSUPER);
    attn_merge6<<<2304, 256, 0, stream>>>(part, mst, lst, out);
  } else if (ws_size >= need_blob1) {
    char* blob = (char*)d_ws;
    prep_blob<<<Bc * NTILES, 256, 0, stream>>>(fm, blob);
    attn_main6<<<80, 256, 0, stream>>>(blob, fq, out, nullptr, nullptr, nullptr, 1, NTILES);
  } else {
    attn_main<<<144, 256, 0, stream>>>(fm, fq, out, NTILES);
  }
}